// Round 3
// baseline (6331.379 us; speedup 1.0000x reference)
//
#include <hip/hip_runtime.h>

#define D 128            // hidden dim
#define DOUT 10

typedef float f32x4 __attribute__((ext_vector_type(4)));
typedef __bf16 bf16x8 __attribute__((ext_vector_type(8)));
typedef unsigned short u16;

__device__ __forceinline__ float bf2f(u16 u) {
    return __uint_as_float(((unsigned int)u) << 16);
}
__device__ __forceinline__ u16 f2bf(float f) {
    unsigned int u = __float_as_uint(f);
    u += 0x7fffu + ((u >> 16) & 1u);
    return (u16)(u >> 16);
}

// ---------------- zero init (bcur | stats | gacc contiguous) ----------------
__global__ void k_zero(float4* __restrict__ p, int n4) {
    int i = blockIdx.x * 256 + threadIdx.x;
    if (i < n4) p[i] = make_float4(0.f, 0.f, 0.f, 0.f);
}

// ---------------- coarse bucket by dst>>7: sequential appends -> no write amp ------
__global__ void k_bucket(const int* __restrict__ src, const int* __restrict__ dst,
                         int* __restrict__ bcur, int2* __restrict__ pairs, int E) {
    int e = blockIdx.x * 256 + threadIdx.x;
    if (e < E) {
        int d = dst[e];
        int b = d >> 7;
        int pos = atomicAdd(&bcur[b], 1);
        if (pos < 4096) pairs[((size_t)b << 12) + pos] = make_int2(d, src[e]);
    }
}

// ---------------- x fp32 -> bf16 (padded rows zeroed) ----------------
__global__ void k_cvt(const float* __restrict__ x, u16* __restrict__ o,
                      int M, int Mpad) {
    long e = ((long)blockIdx.x * 256 + threadIdx.x) * 4;
    if (e >= (long)Mpad * D) return;
    ushort4 r;
    if (e < (long)M * D) {
        float4 v = *(const float4*)(x + e);
        r.x = f2bf(v.x); r.y = f2bf(v.y); r.z = f2bf(v.z); r.w = f2bf(v.w);
    } else {
        r = make_ushort4(0, 0, 0, 0);
    }
    *(ushort4*)(o + e) = r;
}

// ---------------- fused bucket aggregation into LDS ----------------
// block = bucket of 128 dst nodes; 512 thr = 8 waves; 1 edge per wave, unroll x4.
// lane owns channels {lane, lane+64}: ds_add_f32 2-way bank aliasing = free.
__global__ __launch_bounds__(512) void k_agg(
        const u16* __restrict__ h, const int2* __restrict__ pairs,
        const int* __restrict__ bcnt, const float* __restrict__ eps, int layer,
        u16* __restrict__ out, int M, int Mpad) {
    __shared__ float acc[128 * 128];   // 64 KB
    int tid = threadIdx.x;
    for (int i = tid; i < 4096; i += 512)
        ((float4*)acc)[i] = make_float4(0.f, 0.f, 0.f, 0.f);
    __syncthreads();

    int b = blockIdx.x;
    int cnt = bcnt[b];
    if (cnt > 4096) cnt = 4096;
    int wave = tid >> 6, lane = tid & 63;
    const int2* pb = pairs + ((size_t)b << 12);

    int base = 0;
    for (; base + 32 <= cnt; base += 32) {
        int e = base + (wave << 2);
        int2 p0 = pb[e], p1 = pb[e + 1], p2 = pb[e + 2], p3 = pb[e + 3];
        const u16* h0 = h + ((size_t)p0.y << 7) + lane;
        const u16* h1 = h + ((size_t)p1.y << 7) + lane;
        const u16* h2 = h + ((size_t)p2.y << 7) + lane;
        const u16* h3 = h + ((size_t)p3.y << 7) + lane;
        u16 a0 = h0[0], c0 = h0[64];
        u16 a1 = h1[0], c1 = h1[64];
        u16 a2 = h2[0], c2 = h2[64];
        u16 a3 = h3[0], c3 = h3[64];
        int r0 = (p0.x & 127) << 7, r1 = (p1.x & 127) << 7;
        int r2 = (p2.x & 127) << 7, r3 = (p3.x & 127) << 7;
        atomicAdd(&acc[r0 + lane], bf2f(a0));
        atomicAdd(&acc[r0 + 64 + lane], bf2f(c0));
        atomicAdd(&acc[r1 + lane], bf2f(a1));
        atomicAdd(&acc[r1 + 64 + lane], bf2f(c1));
        atomicAdd(&acc[r2 + lane], bf2f(a2));
        atomicAdd(&acc[r2 + 64 + lane], bf2f(c2));
        atomicAdd(&acc[r3 + lane], bf2f(a3));
        atomicAdd(&acc[r3 + 64 + lane], bf2f(c3));
    }
    for (int e = base + wave; e < cnt; e += 8) {
        int2 p = pb[e];
        const u16* hp = h + ((size_t)p.y << 7) + lane;
        u16 a = hp[0], c = hp[64];
        int r = (p.x & 127) << 7;
        atomicAdd(&acc[r + lane], bf2f(a));
        atomicAdd(&acc[r + 64 + lane], bf2f(c));
    }
    __syncthreads();

    // epilogue: pooled = acc + (1+eps)*h[node]; pad rows -> 0
    float e1 = 1.0f + eps[layer];
    int row = tid >> 2;
    int cq = (tid & 3) << 5;
    int node = (b << 7) + row;
    if (node < Mpad) {
        u16* op = out + ((size_t)node << 7) + cq;
        if (node < M) {
            const u16* sp = h + ((size_t)node << 7) + cq;
#pragma unroll
            for (int j = 0; j < 8; ++j) {
                float4 v = *(float4*)&acc[(row << 7) + cq + (j << 2)];
                ushort4 sv = *(const ushort4*)(sp + (j << 2));
                ushort4 r;
                r.x = f2bf(v.x + e1 * bf2f(sv.x));
                r.y = f2bf(v.y + e1 * bf2f(sv.y));
                r.z = f2bf(v.z + e1 * bf2f(sv.z));
                r.w = f2bf(v.w + e1 * bf2f(sv.w));
                *(ushort4*)(op + (j << 2)) = r;
            }
        } else {
#pragma unroll
            for (int j = 0; j < 8; ++j)
                *(ushort4*)(op + (j << 2)) = make_ushort4(0, 0, 0, 0);
        }
    }
}

// ---------------- GEMM1: A(bf16) @ W + b -> O(bf16) + fused BN stats (fp32) --------
__global__ __launch_bounds__(256, 4) void k_gemm_bf(
        const u16* __restrict__ A, u16* __restrict__ O,
        const float* __restrict__ W, const float* __restrict__ bias,
        float* __restrict__ stats, int M) {
    __shared__ bf16x8 wlds[2048];   // B-frag swizzled, 32 KB
    __shared__ float blds[D], ssum[D], ssq[D];
    int tid = threadIdx.x;
    for (int idx = tid; idx < 2048; idx += 256) {
        int lane_s = idx & 63;
        int f = idx >> 6;
        int n = ((f >> 2) << 4) | (lane_s & 15);
        int kb = ((f & 3) << 5) | ((lane_s >> 4) << 3);
        bf16x8 fr;
#pragma unroll
        for (int j = 0; j < 8; ++j) fr[j] = (__bf16)W[(kb + j) * D + n];
        wlds[idx] = fr;
    }
    if (tid < D) { blds[tid] = bias[tid]; ssum[tid] = 0.f; ssq[tid] = 0.f; }
    __syncthreads();

    int wave = tid >> 6, lane = tid & 63;
    int m = lane & 15, quad = lane >> 4;
    int row0 = blockIdx.x * 64 + wave * 16;

    f32x4 z = {0.f, 0.f, 0.f, 0.f};
    f32x4 acc[8];
#pragma unroll
    for (int t = 0; t < 8; ++t) acc[t] = z;

    const u16* ap = A + (size_t)(row0 + m) * D + (quad << 3);
#pragma unroll
    for (int kc = 0; kc < 4; ++kc) {
        bf16x8 af = *(const bf16x8*)(ap + (kc << 5));
#pragma unroll
        for (int t = 0; t < 8; ++t)
            acc[t] = __builtin_amdgcn_mfma_f32_16x16x32_bf16(
                af, wlds[(((t << 2) | kc) << 6) | lane], acc[t], 0, 0, 0);
    }

    int rbase = row0 + (quad << 2);
#pragma unroll
    for (int t = 0; t < 8; ++t) {
        int cch = (t << 4) | m;
        float bc = blds[cch];
        float s = 0.f, q = 0.f;
#pragma unroll
        for (int r = 0; r < 4; ++r) {
            int row = rbase + r;
            float v = acc[t][r] + bc;
            if (row < M) {
                O[(size_t)row * D + cch] = f2bf(v);
                s += v; q += v * v;
            }
        }
        s += __shfl_xor(s, 16); s += __shfl_xor(s, 32);
        q += __shfl_xor(q, 16); q += __shfl_xor(q, 32);
        if (quad == 0) { atomicAdd(&ssum[cch], s); atomicAdd(&ssq[cch], q); }
    }
    __syncthreads();
    if (tid < D) {
        atomicAdd(&stats[tid], ssum[tid]);
        atomicAdd(&stats[D + tid], ssq[tid]);
    }
}

// ---------------- GEMM2: A(bf16) -> BN1+ReLU on the fly -> @W + b, in-place, +stats2
__global__ __launch_bounds__(256, 4) void k_gemm_bn(
        u16* __restrict__ A, const float* __restrict__ W,
        const float* __restrict__ bias, const float* __restrict__ stats_in,
        const float* __restrict__ gamma, const float* __restrict__ beta,
        float* __restrict__ stats_out, float invM, int M) {
    __shared__ bf16x8 wlds[2048];
    __shared__ float blds[D], s_sc[D], s_sh[D], ssum[D], ssq[D];
    int tid = threadIdx.x;
    for (int idx = tid; idx < 2048; idx += 256) {
        int lane_s = idx & 63;
        int f = idx >> 6;
        int n = ((f >> 2) << 4) | (lane_s & 15);
        int kb = ((f & 3) << 5) | ((lane_s >> 4) << 3);
        bf16x8 fr;
#pragma unroll
        for (int j = 0; j < 8; ++j) fr[j] = (__bf16)W[(kb + j) * D + n];
        wlds[idx] = fr;
    }
    if (tid < D) {
        float mean = stats_in[tid] * invM;
        float var = stats_in[D + tid] * invM - mean * mean;
        float sc = rsqrtf(var + 1e-5f) * gamma[tid];
        s_sc[tid] = sc;
        s_sh[tid] = beta[tid] - mean * sc;
        blds[tid] = bias[tid];
        ssum[tid] = 0.f; ssq[tid] = 0.f;
    }
    __syncthreads();

    int wave = tid >> 6, lane = tid & 63;
    int m = lane & 15, quad = lane >> 4;
    int row0 = blockIdx.x * 64 + wave * 16;

    f32x4 z = {0.f, 0.f, 0.f, 0.f};
    f32x4 acc[8];
#pragma unroll
    for (int t = 0; t < 8; ++t) acc[t] = z;

    const u16* ap = A + (size_t)(row0 + m) * D + (quad << 3);
#pragma unroll
    for (int kc = 0; kc < 4; ++kc) {
        int kb = (kc << 5) | (quad << 3);
        ushort4 p0 = *(const ushort4*)(ap + (kc << 5));
        ushort4 p1 = *(const ushort4*)(ap + (kc << 5) + 4);
        float4 c0 = *(const float4*)&s_sc[kb];
        float4 c1 = *(const float4*)&s_sc[kb + 4];
        float4 h0 = *(const float4*)&s_sh[kb];
        float4 h1 = *(const float4*)&s_sh[kb + 4];
        bf16x8 af;
        af[0] = (__bf16)fmaxf(0.f, fmaf(bf2f(p0.x), c0.x, h0.x));
        af[1] = (__bf16)fmaxf(0.f, fmaf(bf2f(p0.y), c0.y, h0.y));
        af[2] = (__bf16)fmaxf(0.f, fmaf(bf2f(p0.z), c0.z, h0.z));
        af[3] = (__bf16)fmaxf(0.f, fmaf(bf2f(p0.w), c0.w, h0.w));
        af[4] = (__bf16)fmaxf(0.f, fmaf(bf2f(p1.x), c1.x, h1.x));
        af[5] = (__bf16)fmaxf(0.f, fmaf(bf2f(p1.y), c1.y, h1.y));
        af[6] = (__bf16)fmaxf(0.f, fmaf(bf2f(p1.z), c1.z, h1.z));
        af[7] = (__bf16)fmaxf(0.f, fmaf(bf2f(p1.w), c1.w, h1.w));
#pragma unroll
        for (int t = 0; t < 8; ++t)
            acc[t] = __builtin_amdgcn_mfma_f32_16x16x32_bf16(
                af, wlds[(((t << 2) | kc) << 6) | lane], acc[t], 0, 0, 0);
    }

    int rbase = row0 + (quad << 2);
#pragma unroll
    for (int t = 0; t < 8; ++t) {
        int cch = (t << 4) | m;
        float bc = blds[cch];
        float s = 0.f, q = 0.f;
#pragma unroll
        for (int r = 0; r < 4; ++r) {
            int row = rbase + r;
            float v = acc[t][r] + bc;
            if (row < M) {
                A[(size_t)row * D + cch] = f2bf(v);
                s += v; q += v * v;
            }
        }
        s += __shfl_xor(s, 16); s += __shfl_xor(s, 32);
        q += __shfl_xor(q, 16); q += __shfl_xor(q, 32);
        if (quad == 0) { atomicAdd(&ssum[cch], s); atomicAdd(&ssq[cch], q); }
    }
    __syncthreads();
    if (tid < D) {
        atomicAdd(&stats_out[tid], ssum[tid]);
        atomicAdd(&stats_out[D + tid], ssq[tid]);
    }
}

// ---------------- BN2 + ReLU -> bf16 h, + fused weighted graph pooling ----------------
__global__ void k_bn2pool(const u16* __restrict__ y, const float* __restrict__ stats,
                          const float* __restrict__ gamma, const float* __restrict__ beta,
                          const int* __restrict__ gids, const float* __restrict__ fw,
                          int layer, u16* __restrict__ hout,
                          float* __restrict__ gacc, float invM, int M) {
    int c = threadIdx.x;  // 128 threads
    long base = (long)blockIdx.x * 64;
    long nend = base + 64; if (nend > M) nend = M;
    float mean = stats[c] * invM;
    float sc = rsqrtf(stats[D + c] * invM - mean * mean + 1e-5f) * gamma[c];
    float sh = beta[c] - mean * sc;
    float wl = fw[layer];
    int cur = -1;
    float acc = 0.f;
    for (long node = base; node < nend; ++node) {
        float hn = fmaxf(0.f, fmaf(bf2f(y[node * D + c]), sc, sh));
        hout[node * D + c] = f2bf(hn);
        int gid = gids[node];
        if (gid != cur) {
            if (cur >= 0) atomicAdd(&gacc[(size_t)cur * D + c], wl * acc);
            cur = gid;
            acc = 0.f;
        }
        acc += hn;
    }
    if (cur >= 0) atomicAdd(&gacc[(size_t)cur * D + c], wl * acc);
}

// ---------------- final: out = gacc(Gx128) @ Wp(128x10) + bp ----------------
__global__ void k_final(const float* __restrict__ gacc, const float* __restrict__ Wp,
                        const float* __restrict__ bp, float* __restrict__ out) {
    __shared__ float w[D * DOUT];
    __shared__ float bb[DOUT];
    int t = threadIdx.x;
    for (int i = t; i < D * DOUT; i += blockDim.x) w[i] = Wp[i];
    if (t < DOUT) bb[t] = bp[t];
    __syncthreads();
    float acc[DOUT];
#pragma unroll
    for (int o = 0; o < DOUT; ++o) acc[o] = bb[o];
    for (int k = 0; k < D; ++k) {
        float a = gacc[(size_t)t * D + k];
#pragma unroll
        for (int o = 0; o < DOUT; ++o) acc[o] += a * w[k * DOUT + o];
    }
#pragma unroll
    for (int o = 0; o < DOUT; ++o) out[(size_t)t * DOUT + o] = acc[o];
}

extern "C" void kernel_launch(void* const* d_in, const int* in_sizes, int n_in,
                              void* d_out, int out_size, void* d_ws, size_t ws_size,
                              hipStream_t stream) {
    const float* x    = (const float*)d_in[0];
    const int* esrc   = (const int*)d_in[1];
    const int* edst   = (const int*)d_in[2];
    const int* gids   = (const int*)d_in[3];
    const float* eps  = (const float*)d_in[4];
    const float* fw   = (const float*)d_in[5];
    const float* W1   = (const float*)d_in[6];
    const float* b1   = (const float*)d_in[7];
    const float* g1   = (const float*)d_in[8];
    const float* bt1  = (const float*)d_in[9];
    const float* W2   = (const float*)d_in[10];
    const float* b2   = (const float*)d_in[11];
    const float* g2   = (const float*)d_in[12];
    const float* bt2  = (const float*)d_in[13];
    const float* Wp   = (const float*)d_in[14];
    const float* bp   = (const float*)d_in[15];
    float* out        = (float*)d_out;

    const int M = in_sizes[3];     // 100000 nodes
    const int E = in_sizes[1];     // 1600000 edges
    const int L = in_sizes[4];     // 4 layers
    const int G = out_size / DOUT; // 256 graphs
    const int Mpad = ((M + 63) / 64) * 64;
    const int nb = (M + 127) >> 7;            // buckets of 128 dst nodes
    const float invM = 1.0f / (float)M;

    char* ws = (char*)d_ws;
    u16* bufP  = (u16*)ws;  ws += (size_t)Mpad * D * 2;   // pooled bf16
    u16* bufT  = (u16*)ws;  ws += (size_t)Mpad * D * 2;   // MLP temp bf16
    u16* bufH  = (u16*)ws;  ws += (size_t)Mpad * D * 2;   // hidden bf16
    int2* pairs = (int2*)ws; ws += (size_t)nb * 4096 * 8; // bucketed (dst,src)
    // contiguous zero region: bcur (1024 ints) | stats | gacc
    int* bcur   = (int*)ws;   ws += 1024 * 4;
    float* stats = (float*)ws; ws += (size_t)L * 512 * 4;
    float* gacc  = (float*)ws; ws += (size_t)G * D * 4;

    int zbytes = 1024 * 4 + L * 512 * 4 + G * D * 4;
    int n4 = zbytes / 16;
    k_zero<<<(n4 + 255) / 256, 256, 0, stream>>>((float4*)bcur, n4);

    k_bucket<<<(E + 255) / 256, 256, 0, stream>>>(esrc, edst, bcur, pairs, E);
    k_cvt<<<(Mpad * (D / 4) + 255) / 256, 256, 0, stream>>>(x, bufH, M, Mpad);

    int gemm_grid = Mpad / 64;
    int pool_grid = (M + 63) / 64;
    for (int l = 0; l < L; ++l) {
        float* st1 = stats + (size_t)l * 512;
        float* st2 = st1 + 256;
        k_agg<<<nb, 512, 0, stream>>>(bufH, pairs, bcur, eps, l, bufP, M, Mpad);
        k_gemm_bf<<<gemm_grid, 256, 0, stream>>>(bufP, bufT, W1 + (size_t)l * D * D,
                                                 b1 + (size_t)l * D, st1, M);
        k_gemm_bn<<<gemm_grid, 256, 0, stream>>>(bufT, W2 + (size_t)l * D * D,
                                                 b2 + (size_t)l * D, st1,
                                                 g1 + (size_t)l * D, bt1 + (size_t)l * D,
                                                 st2, invM, M);
        k_bn2pool<<<pool_grid, 128, 0, stream>>>(bufT, st2, g2 + (size_t)l * D,
                                                 bt2 + (size_t)l * D, gids, fw, l,
                                                 bufH, gacc, invM, M);
    }
    k_final<<<1, G, 0, stream>>>(gacc, Wp, bp, out);
}

// Round 4
// 1361.463 us; speedup vs baseline: 4.6504x; 4.6504x over previous
//
#include <hip/hip_runtime.h>

#define D 128            // hidden dim
#define DOUT 10

typedef float f32x4 __attribute__((ext_vector_type(4)));
typedef __bf16 bf16x8 __attribute__((ext_vector_type(8)));
typedef unsigned short u16;

__device__ __forceinline__ float bf2f(u16 u) {
    return __uint_as_float(((unsigned int)u) << 16);
}
__device__ __forceinline__ u16 f2bf(float f) {
    unsigned int u = __float_as_uint(f);
    u += 0x7fffu + ((u >> 16) & 1u);
    return (u16)(u >> 16);
}

// ---------------- zero init (bcur | stats | gacc contiguous) ----------------
__global__ void k_zero(float4* __restrict__ p, int n4) {
    int i = blockIdx.x * 256 + threadIdx.x;
    if (i < n4) p[i] = make_float4(0.f, 0.f, 0.f, 0.f);
}

// ---------------- coarse bucket by dst>>7: sequential appends -> no write amp ------
__global__ void k_bucket(const int* __restrict__ src, const int* __restrict__ dst,
                         int* __restrict__ bcur, int2* __restrict__ pairs, int E) {
    int e = blockIdx.x * 256 + threadIdx.x;
    if (e < E) {
        int d = dst[e];
        int b = d >> 7;
        int pos = atomicAdd(&bcur[b], 1);
        if (pos < 4096) pairs[((size_t)b << 12) + pos] = make_int2(d, src[e]);
    }
}

// ---------------- x fp32 -> bf16 (padded rows zeroed) ----------------
__global__ void k_cvt(const float* __restrict__ x, u16* __restrict__ o,
                      int M, int Mpad) {
    long e = ((long)blockIdx.x * 256 + threadIdx.x) * 4;
    if (e >= (long)Mpad * D) return;
    ushort4 r;
    if (e < (long)M * D) {
        float4 v = *(const float4*)(x + e);
        r.x = f2bf(v.x); r.y = f2bf(v.y); r.z = f2bf(v.z); r.w = f2bf(v.w);
    } else {
        r = make_ushort4(0, 0, 0, 0);
    }
    *(ushort4*)(o + e) = r;
}

// ---------------- bucket aggregation: local CSR in LDS, register accumulation -----
// one block per bucket of 128 dst nodes; 512 thr = 8 waves = 16 half-wave groups.
// NO fp32 LDS atomics (round-3 lesson: they serialize catastrophically);
// histogram uses native int ds_add, gather accumulates in registers.
__global__ __launch_bounds__(512) void k_agg(
        const u16* __restrict__ h, const int2* __restrict__ pairs,
        const int* __restrict__ bcnt, const float* __restrict__ eps, int layer,
        u16* __restrict__ out, int M, int Mpad) {
    __shared__ int lcnt[128];
    __shared__ int loff[128];   // inclusive scan
    __shared__ int lcur[128];
    __shared__ int ledge[4096]; // 16 KB local edge list (src indices, grouped by dst)
    int tid = threadIdx.x;
    if (tid < 128) lcnt[tid] = 0;
    __syncthreads();

    int b = blockIdx.x;
    int cnt = bcnt[b];
    if (cnt > 4096) cnt = 4096;
    const int2* pb = pairs + ((size_t)b << 12);

    // phase 1: histogram (native int LDS atomics)
    for (int e = tid; e < cnt; e += 512)
        atomicAdd(&lcnt[pb[e].x & 127], 1);
    __syncthreads();

    // phase 2: inclusive Hillis-Steele scan over 128 counts
    if (tid < 128) loff[tid] = lcnt[tid];
    __syncthreads();
    for (int off = 1; off < 128; off <<= 1) {
        int v = 0;
        if (tid < 128 && tid >= off) v = loff[tid - off];
        __syncthreads();
        if (tid < 128) loff[tid] += v;
        __syncthreads();
    }
    if (tid < 128) lcur[tid] = loff[tid] - lcnt[tid];   // exclusive start
    __syncthreads();

    // phase 3: scatter src indices into local CSR
    for (int e = tid; e < cnt; e += 512) {
        int2 p = pb[e];
        int pos = atomicAdd(&lcur[p.x & 127], 1);
        ledge[pos] = p.y;
    }
    __syncthreads();

    // phase 4: node-parallel gather; 16 groups of 32 lanes, 8 passes over 128 rows
    float e1 = 1.0f + eps[layer];
    int grp = tid >> 5;
    int c = (tid & 31) << 2;   // 4 channels per lane (ushort4)
    for (int pass = 0; pass < 8; ++pass) {
        int row = (pass << 4) + grp;
        int node = (b << 7) + row;
        if (node >= Mpad) continue;
        u16* op = out + ((size_t)node << 7) + c;
        if (node >= M) { *(ushort4*)op = make_ushort4(0, 0, 0, 0); continue; }
        ushort4 sv = *(const ushort4*)(h + ((size_t)node << 7) + c);
        float a0 = e1 * bf2f(sv.x), a1 = e1 * bf2f(sv.y);
        float a2 = e1 * bf2f(sv.z), a3 = e1 * bf2f(sv.w);
        int dd = lcnt[row];
        int s = loff[row] - dd;
        int i = 0;
        for (; i + 4 <= dd; i += 4) {
            int n0 = ledge[s + i],     n1 = ledge[s + i + 1];
            int n2 = ledge[s + i + 2], n3 = ledge[s + i + 3];
            ushort4 u0 = *(const ushort4*)(h + ((size_t)n0 << 7) + c);
            ushort4 u1 = *(const ushort4*)(h + ((size_t)n1 << 7) + c);
            ushort4 u2 = *(const ushort4*)(h + ((size_t)n2 << 7) + c);
            ushort4 u3 = *(const ushort4*)(h + ((size_t)n3 << 7) + c);
            a0 += bf2f(u0.x) + bf2f(u1.x) + bf2f(u2.x) + bf2f(u3.x);
            a1 += bf2f(u0.y) + bf2f(u1.y) + bf2f(u2.y) + bf2f(u3.y);
            a2 += bf2f(u0.z) + bf2f(u1.z) + bf2f(u2.z) + bf2f(u3.z);
            a3 += bf2f(u0.w) + bf2f(u1.w) + bf2f(u2.w) + bf2f(u3.w);
        }
        for (; i < dd; ++i) {
            int n0 = ledge[s + i];
            ushort4 u0 = *(const ushort4*)(h + ((size_t)n0 << 7) + c);
            a0 += bf2f(u0.x); a1 += bf2f(u0.y); a2 += bf2f(u0.z); a3 += bf2f(u0.w);
        }
        ushort4 r;
        r.x = f2bf(a0); r.y = f2bf(a1); r.z = f2bf(a2); r.w = f2bf(a3);
        *(ushort4*)op = r;
    }
}

// ---------------- GEMM1: A(bf16) @ W + b -> O(bf16) + fused BN stats (fp32) --------
__global__ __launch_bounds__(256, 4) void k_gemm_bf(
        const u16* __restrict__ A, u16* __restrict__ O,
        const float* __restrict__ W, const float* __restrict__ bias,
        float* __restrict__ stats, int M) {
    __shared__ bf16x8 wlds[2048];   // B-frag swizzled, 32 KB
    __shared__ float blds[D], ssum[D], ssq[D];
    int tid = threadIdx.x;
    for (int idx = tid; idx < 2048; idx += 256) {
        int lane_s = idx & 63;
        int f = idx >> 6;
        int n = ((f >> 2) << 4) | (lane_s & 15);
        int kb = ((f & 3) << 5) | ((lane_s >> 4) << 3);
        bf16x8 fr;
#pragma unroll
        for (int j = 0; j < 8; ++j) fr[j] = (__bf16)W[(kb + j) * D + n];
        wlds[idx] = fr;
    }
    if (tid < D) { blds[tid] = bias[tid]; ssum[tid] = 0.f; ssq[tid] = 0.f; }
    __syncthreads();

    int wave = tid >> 6, lane = tid & 63;
    int m = lane & 15, quad = lane >> 4;
    int row0 = blockIdx.x * 64 + wave * 16;

    f32x4 z = {0.f, 0.f, 0.f, 0.f};
    f32x4 acc[8];
#pragma unroll
    for (int t = 0; t < 8; ++t) acc[t] = z;

    const u16* ap = A + (size_t)(row0 + m) * D + (quad << 3);
#pragma unroll
    for (int kc = 0; kc < 4; ++kc) {
        bf16x8 af = *(const bf16x8*)(ap + (kc << 5));
#pragma unroll
        for (int t = 0; t < 8; ++t)
            acc[t] = __builtin_amdgcn_mfma_f32_16x16x32_bf16(
                af, wlds[(((t << 2) | kc) << 6) | lane], acc[t], 0, 0, 0);
    }

    int rbase = row0 + (quad << 2);
#pragma unroll
    for (int t = 0; t < 8; ++t) {
        int cch = (t << 4) | m;
        float bc = blds[cch];
        float s = 0.f, q = 0.f;
#pragma unroll
        for (int r = 0; r < 4; ++r) {
            int row = rbase + r;
            float v = acc[t][r] + bc;
            if (row < M) {
                O[(size_t)row * D + cch] = f2bf(v);
                s += v; q += v * v;
            }
        }
        s += __shfl_xor(s, 16); s += __shfl_xor(s, 32);
        q += __shfl_xor(q, 16); q += __shfl_xor(q, 32);
        if (quad == 0) { atomicAdd(&ssum[cch], s); atomicAdd(&ssq[cch], q); }
    }
    __syncthreads();
    if (tid < D) {
        atomicAdd(&stats[tid], ssum[tid]);
        atomicAdd(&stats[D + tid], ssq[tid]);
    }
}

// ---------------- GEMM2: A(bf16) -> BN1+ReLU on the fly -> @W + b, in-place, +stats2
__global__ __launch_bounds__(256, 4) void k_gemm_bn(
        u16* __restrict__ A, const float* __restrict__ W,
        const float* __restrict__ bias, const float* __restrict__ stats_in,
        const float* __restrict__ gamma, const float* __restrict__ beta,
        float* __restrict__ stats_out, float invM, int M) {
    __shared__ bf16x8 wlds[2048];
    __shared__ float blds[D], s_sc[D], s_sh[D], ssum[D], ssq[D];
    int tid = threadIdx.x;
    for (int idx = tid; idx < 2048; idx += 256) {
        int lane_s = idx & 63;
        int f = idx >> 6;
        int n = ((f >> 2) << 4) | (lane_s & 15);
        int kb = ((f & 3) << 5) | ((lane_s >> 4) << 3);
        bf16x8 fr;
#pragma unroll
        for (int j = 0; j < 8; ++j) fr[j] = (__bf16)W[(kb + j) * D + n];
        wlds[idx] = fr;
    }
    if (tid < D) {
        float mean = stats_in[tid] * invM;
        float var = stats_in[D + tid] * invM - mean * mean;
        float sc = rsqrtf(var + 1e-5f) * gamma[tid];
        s_sc[tid] = sc;
        s_sh[tid] = beta[tid] - mean * sc;
        blds[tid] = bias[tid];
        ssum[tid] = 0.f; ssq[tid] = 0.f;
    }
    __syncthreads();

    int wave = tid >> 6, lane = tid & 63;
    int m = lane & 15, quad = lane >> 4;
    int row0 = blockIdx.x * 64 + wave * 16;

    f32x4 z = {0.f, 0.f, 0.f, 0.f};
    f32x4 acc[8];
#pragma unroll
    for (int t = 0; t < 8; ++t) acc[t] = z;

    const u16* ap = A + (size_t)(row0 + m) * D + (quad << 3);
#pragma unroll
    for (int kc = 0; kc < 4; ++kc) {
        int kb = (kc << 5) | (quad << 3);
        ushort4 p0 = *(const ushort4*)(ap + (kc << 5));
        ushort4 p1 = *(const ushort4*)(ap + (kc << 5) + 4);
        float4 c0 = *(const float4*)&s_sc[kb];
        float4 c1 = *(const float4*)&s_sc[kb + 4];
        float4 h0 = *(const float4*)&s_sh[kb];
        float4 h1 = *(const float4*)&s_sh[kb + 4];
        bf16x8 af;
        af[0] = (__bf16)fmaxf(0.f, fmaf(bf2f(p0.x), c0.x, h0.x));
        af[1] = (__bf16)fmaxf(0.f, fmaf(bf2f(p0.y), c0.y, h0.y));
        af[2] = (__bf16)fmaxf(0.f, fmaf(bf2f(p0.z), c0.z, h0.z));
        af[3] = (__bf16)fmaxf(0.f, fmaf(bf2f(p0.w), c0.w, h0.w));
        af[4] = (__bf16)fmaxf(0.f, fmaf(bf2f(p1.x), c1.x, h1.x));
        af[5] = (__bf16)fmaxf(0.f, fmaf(bf2f(p1.y), c1.y, h1.y));
        af[6] = (__bf16)fmaxf(0.f, fmaf(bf2f(p1.z), c1.z, h1.z));
        af[7] = (__bf16)fmaxf(0.f, fmaf(bf2f(p1.w), c1.w, h1.w));
#pragma unroll
        for (int t = 0; t < 8; ++t)
            acc[t] = __builtin_amdgcn_mfma_f32_16x16x32_bf16(
                af, wlds[(((t << 2) | kc) << 6) | lane], acc[t], 0, 0, 0);
    }

    int rbase = row0 + (quad << 2);
#pragma unroll
    for (int t = 0; t < 8; ++t) {
        int cch = (t << 4) | m;
        float bc = blds[cch];
        float s = 0.f, q = 0.f;
#pragma unroll
        for (int r = 0; r < 4; ++r) {
            int row = rbase + r;
            float v = acc[t][r] + bc;
            if (row < M) {
                A[(size_t)row * D + cch] = f2bf(v);
                s += v; q += v * v;
            }
        }
        s += __shfl_xor(s, 16); s += __shfl_xor(s, 32);
        q += __shfl_xor(q, 16); q += __shfl_xor(q, 32);
        if (quad == 0) { atomicAdd(&ssum[cch], s); atomicAdd(&ssq[cch], q); }
    }
    __syncthreads();
    if (tid < D) {
        atomicAdd(&stats_out[tid], ssum[tid]);
        atomicAdd(&stats_out[D + tid], ssq[tid]);
    }
}

// ---------------- BN2 + ReLU -> bf16 h, + fused weighted graph pooling ----------------
// 256 thr: 8 strips x 8 rows; lane handles 4 channels (ushort4)
__global__ __launch_bounds__(256) void k_bn2pool(
        const u16* __restrict__ y, const float* __restrict__ stats,
        const float* __restrict__ gamma, const float* __restrict__ beta,
        const int* __restrict__ gids, const float* __restrict__ fw,
        int layer, u16* __restrict__ hout, float* __restrict__ gacc,
        float invM, int M) {
    int t = threadIdx.x;
    int c = (t & 31) << 2;
    int strip = t >> 5;
    long base = (long)blockIdx.x * 64 + (long)strip * 8;
    if (base >= M) return;
    long nend = base + 8; if (nend > M) nend = M;
    float sc[4], sh[4];
#pragma unroll
    for (int j = 0; j < 4; ++j) {
        float mean = stats[c + j] * invM;
        float s = rsqrtf(stats[D + c + j] * invM - mean * mean + 1e-5f) * gamma[c + j];
        sc[j] = s;
        sh[j] = beta[c + j] - mean * s;
    }
    float wl = fw[layer];
    int cur = -1;
    float a0 = 0.f, a1 = 0.f, a2 = 0.f, a3 = 0.f;
    for (long node = base; node < nend; ++node) {
        ushort4 v = *(const ushort4*)(y + (node << 7) + c);
        float h0 = fmaxf(0.f, fmaf(bf2f(v.x), sc[0], sh[0]));
        float h1 = fmaxf(0.f, fmaf(bf2f(v.y), sc[1], sh[1]));
        float h2 = fmaxf(0.f, fmaf(bf2f(v.z), sc[2], sh[2]));
        float h3 = fmaxf(0.f, fmaf(bf2f(v.w), sc[3], sh[3]));
        ushort4 r;
        r.x = f2bf(h0); r.y = f2bf(h1); r.z = f2bf(h2); r.w = f2bf(h3);
        *(ushort4*)(hout + (node << 7) + c) = r;
        int gid = gids[node];
        if (gid != cur) {
            if (cur >= 0) {
                float* gp = gacc + ((size_t)cur << 7) + c;
                atomicAdd(gp, wl * a0); atomicAdd(gp + 1, wl * a1);
                atomicAdd(gp + 2, wl * a2); atomicAdd(gp + 3, wl * a3);
            }
            cur = gid;
            a0 = a1 = a2 = a3 = 0.f;
        }
        a0 += h0; a1 += h1; a2 += h2; a3 += h3;
    }
    if (cur >= 0) {
        float* gp = gacc + ((size_t)cur << 7) + c;
        atomicAdd(gp, wl * a0); atomicAdd(gp + 1, wl * a1);
        atomicAdd(gp + 2, wl * a2); atomicAdd(gp + 3, wl * a3);
    }
}

// ---------------- final: out = gacc(Gx128) @ Wp(128x10) + bp ----------------
__global__ void k_final(const float* __restrict__ gacc, const float* __restrict__ Wp,
                        const float* __restrict__ bp, float* __restrict__ out) {
    __shared__ float w[D * DOUT];
    __shared__ float bb[DOUT];
    int t = threadIdx.x;
    for (int i = t; i < D * DOUT; i += blockDim.x) w[i] = Wp[i];
    if (t < DOUT) bb[t] = bp[t];
    __syncthreads();
    float acc[DOUT];
#pragma unroll
    for (int o = 0; o < DOUT; ++o) acc[o] = bb[o];
    for (int k = 0; k < D; ++k) {
        float a = gacc[(size_t)t * D + k];
#pragma unroll
        for (int o = 0; o < DOUT; ++o) acc[o] += a * w[k * DOUT + o];
    }
#pragma unroll
    for (int o = 0; o < DOUT; ++o) out[(size_t)t * DOUT + o] = acc[o];
}

extern "C" void kernel_launch(void* const* d_in, const int* in_sizes, int n_in,
                              void* d_out, int out_size, void* d_ws, size_t ws_size,
                              hipStream_t stream) {
    const float* x    = (const float*)d_in[0];
    const int* esrc   = (const int*)d_in[1];
    const int* edst   = (const int*)d_in[2];
    const int* gids   = (const int*)d_in[3];
    const float* eps  = (const float*)d_in[4];
    const float* fw   = (const float*)d_in[5];
    const float* W1   = (const float*)d_in[6];
    const float* b1   = (const float*)d_in[7];
    const float* g1   = (const float*)d_in[8];
    const float* bt1  = (const float*)d_in[9];
    const float* W2   = (const float*)d_in[10];
    const float* b2   = (const float*)d_in[11];
    const float* g2   = (const float*)d_in[12];
    const float* bt2  = (const float*)d_in[13];
    const float* Wp   = (const float*)d_in[14];
    const float* bp   = (const float*)d_in[15];
    float* out        = (float*)d_out;

    const int M = in_sizes[3];     // 100000 nodes
    const int E = in_sizes[1];     // 1600000 edges
    const int L = in_sizes[4];     // 4 layers
    const int G = out_size / DOUT; // 256 graphs
    const int Mpad = ((M + 63) / 64) * 64;
    const int nb = (M + 127) >> 7;            // buckets of 128 dst nodes
    const float invM = 1.0f / (float)M;

    char* ws = (char*)d_ws;
    u16* bufP  = (u16*)ws;  ws += (size_t)Mpad * D * 2;   // pooled bf16
    u16* bufT  = (u16*)ws;  ws += (size_t)Mpad * D * 2;   // MLP temp bf16
    u16* bufH  = (u16*)ws;  ws += (size_t)Mpad * D * 2;   // hidden bf16
    int2* pairs = (int2*)ws; ws += (size_t)nb * 4096 * 8; // bucketed (dst,src)
    // contiguous zero region: bcur (1024 ints) | stats | gacc
    int* bcur   = (int*)ws;   ws += 1024 * 4;
    float* stats = (float*)ws; ws += (size_t)L * 512 * 4;
    float* gacc  = (float*)ws; ws += (size_t)G * D * 4;

    int zbytes = 1024 * 4 + L * 512 * 4 + G * D * 4;
    int n4 = zbytes / 16;
    k_zero<<<(n4 + 255) / 256, 256, 0, stream>>>((float4*)bcur, n4);

    k_bucket<<<(E + 255) / 256, 256, 0, stream>>>(esrc, edst, bcur, pairs, E);
    k_cvt<<<(Mpad * (D / 4) + 255) / 256, 256, 0, stream>>>(x, bufH, M, Mpad);

    int gemm_grid = Mpad / 64;
    int pool_grid = (M + 63) / 64;
    for (int l = 0; l < L; ++l) {
        float* st1 = stats + (size_t)l * 512;
        float* st2 = st1 + 256;
        k_agg<<<nb, 512, 0, stream>>>(bufH, pairs, bcur, eps, l, bufP, M, Mpad);
        k_gemm_bf<<<gemm_grid, 256, 0, stream>>>(bufP, bufT, W1 + (size_t)l * D * D,
                                                 b1 + (size_t)l * D, st1, M);
        k_gemm_bn<<<gemm_grid, 256, 0, stream>>>(bufT, W2 + (size_t)l * D * D,
                                                 b2 + (size_t)l * D, st1,
                                                 g1 + (size_t)l * D, bt1 + (size_t)l * D,
                                                 st2, invM, M);
        k_bn2pool<<<pool_grid, 256, 0, stream>>>(bufT, st2, g2 + (size_t)l * D,
                                                 bt2 + (size_t)l * D, gids, fw, l,
                                                 bufH, gacc, invM, M);
    }
    k_final<<<1, G, 0, stream>>>(gacc, Wp, bp, out);
}

// Round 5
// 1080.347 us; speedup vs baseline: 5.8605x; 1.2602x over previous
//
#include <hip/hip_runtime.h>

#define D 128            // hidden dim
#define DOUT 10

typedef float f32x4 __attribute__((ext_vector_type(4)));
typedef __bf16 bf16x8 __attribute__((ext_vector_type(8)));
typedef unsigned short u16;

__device__ __forceinline__ float bf2f(u16 u) {
    return __uint_as_float(((unsigned int)u) << 16);
}
__device__ __forceinline__ u16 f2bf(float f) {
    unsigned int u = __float_as_uint(f);
    u += 0x7fffu + ((u >> 16) & 1u);
    return (u16)(u >> 16);
}

// ---------------- zero init (stats | gacc contiguous) ----------------
__global__ void k_zero(float4* __restrict__ p, int n4) {
    int i = blockIdx.x * 256 + threadIdx.x;
    if (i < n4) p[i] = make_float4(0.f, 0.f, 0.f, 0.f);
}

// ============ bucketing: deterministic two-level, NO contended global atomics ======
// (round-4 lesson: 1.6M atomic-returns over 782 addresses serialize at ~400cyc each)
// chunk = 16384 edges per block; bucket = dst>>7 (128 dst nodes).

__global__ __launch_bounds__(256) void k_hist(const int* __restrict__ dst,
                                              int* __restrict__ cnts, int E, int nb) {
    __shared__ int hist[1024];
    int tid = threadIdx.x;
    for (int i = tid; i < nb; i += 256) hist[i] = 0;
    __syncthreads();
    int e0 = blockIdx.x << 14;
    int e1 = e0 + 16384; if (e1 > E) e1 = E;
    for (int e = e0 + tid; e < e1; e += 256) atomicAdd(&hist[dst[e] >> 7], 1);
    __syncthreads();
    for (int i = tid; i < nb; i += 256) cnts[(blockIdx.x << 10) + i] = hist[i];
}

// per-bucket exclusive scan across chunk-blocks; totals -> btot
__global__ void k_off(int* __restrict__ cnts, int* __restrict__ btot, int nbk, int nb) {
    int b = blockIdx.x * 256 + threadIdx.x;
    if (b >= nb) return;
    int run = 0;
    for (int k = 0; k < nbk; ++k) {
        int idx = (k << 10) + b;
        int c = cnts[idx];
        cnts[idx] = run;
        run += c;
    }
    btot[b] = run;
}

__global__ __launch_bounds__(256) void k_scat(const int* __restrict__ src,
                                              const int* __restrict__ dst,
                                              const int* __restrict__ cnts,
                                              int* __restrict__ pairs, int E, int nb) {
    __shared__ int lbase[1024];
    __shared__ int lcur[1024];
    int tid = threadIdx.x;
    for (int i = tid; i < nb; i += 256) {
        lbase[i] = cnts[(blockIdx.x << 10) + i];
        lcur[i] = 0;
    }
    __syncthreads();
    int e0 = blockIdx.x << 14;
    int e1 = e0 + 16384; if (e1 > E) e1 = E;
    for (int e = e0 + tid; e < e1; e += 256) {
        int d = dst[e];
        int b = d >> 7;
        int pos = lbase[b] + atomicAdd(&lcur[b], 1);
        if (pos < 4096) pairs[(b << 12) + pos] = (src[e] << 7) | (d & 127);
    }
}

// ---------------- x fp32 -> bf16 (padded rows zeroed) ----------------
__global__ void k_cvt(const float* __restrict__ x, u16* __restrict__ o,
                      int M, int Mpad) {
    long e = ((long)blockIdx.x * 256 + threadIdx.x) * 4;
    if (e >= (long)Mpad * D) return;
    ushort4 r;
    if (e < (long)M * D) {
        float4 v = *(const float4*)(x + e);
        r.x = f2bf(v.x); r.y = f2bf(v.y); r.z = f2bf(v.z); r.w = f2bf(v.w);
    } else {
        r = make_ushort4(0, 0, 0, 0);
    }
    *(ushort4*)(o + e) = r;
}

// ---------------- bucket aggregation: local CSR in LDS, register accumulation -----
// one block per bucket of 128 dst nodes; 512 thr = 8 waves = 16 half-wave groups.
// gather unrolled 8-deep (+4 mid-tier) to maximize outstanding L3 loads.
__global__ __launch_bounds__(512) void k_agg(
        const u16* __restrict__ h, const int* __restrict__ pairs,
        const int* __restrict__ bcnt, const float* __restrict__ eps, int layer,
        u16* __restrict__ out, int M, int Mpad) {
    __shared__ int lcnt[128];
    __shared__ int loff[128];   // inclusive scan
    __shared__ int lcur[128];
    __shared__ int ledge[4096]; // 16 KB local edge list (src indices, grouped by dst)
    int tid = threadIdx.x;
    if (tid < 128) lcnt[tid] = 0;
    __syncthreads();

    int b = blockIdx.x;
    int cnt = bcnt[b];
    if (cnt > 4096) cnt = 4096;
    const int* pb = pairs + ((size_t)b << 12);

    // phase 1: histogram (native int LDS atomics)
    for (int e = tid; e < cnt; e += 512)
        atomicAdd(&lcnt[pb[e] & 127], 1);
    __syncthreads();

    // phase 2: inclusive Hillis-Steele scan over 128 counts
    if (tid < 128) loff[tid] = lcnt[tid];
    __syncthreads();
    for (int off = 1; off < 128; off <<= 1) {
        int v = 0;
        if (tid < 128 && tid >= off) v = loff[tid - off];
        __syncthreads();
        if (tid < 128) loff[tid] += v;
        __syncthreads();
    }
    if (tid < 128) lcur[tid] = loff[tid] - lcnt[tid];   // exclusive start
    __syncthreads();

    // phase 3: scatter src indices into local CSR
    for (int e = tid; e < cnt; e += 512) {
        int p = pb[e];
        int pos = atomicAdd(&lcur[p & 127], 1);
        ledge[pos] = p >> 7;
    }
    __syncthreads();

    // phase 4: node-parallel gather; 16 groups of 32 lanes, 8 passes over 128 rows
    float e1 = 1.0f + eps[layer];
    int grp = tid >> 5;
    int c = (tid & 31) << 2;   // 4 channels per lane (ushort4)
    for (int pass = 0; pass < 8; ++pass) {
        int row = (pass << 4) + grp;
        int node = (b << 7) + row;
        if (node >= Mpad) continue;
        u16* op = out + ((size_t)node << 7) + c;
        if (node >= M) { *(ushort4*)op = make_ushort4(0, 0, 0, 0); continue; }
        ushort4 sv = *(const ushort4*)(h + ((size_t)node << 7) + c);
        float a0 = e1 * bf2f(sv.x), a1 = e1 * bf2f(sv.y);
        float a2 = e1 * bf2f(sv.z), a3 = e1 * bf2f(sv.w);
        int dd = lcnt[row];
        int s = loff[row] - dd;
        int i = 0;
        for (; i + 8 <= dd; i += 8) {
            int n0 = ledge[s + i],     n1 = ledge[s + i + 1];
            int n2 = ledge[s + i + 2], n3 = ledge[s + i + 3];
            int n4 = ledge[s + i + 4], n5 = ledge[s + i + 5];
            int n6 = ledge[s + i + 6], n7 = ledge[s + i + 7];
            ushort4 u0 = *(const ushort4*)(h + ((size_t)n0 << 7) + c);
            ushort4 u1 = *(const ushort4*)(h + ((size_t)n1 << 7) + c);
            ushort4 u2 = *(const ushort4*)(h + ((size_t)n2 << 7) + c);
            ushort4 u3 = *(const ushort4*)(h + ((size_t)n3 << 7) + c);
            ushort4 u4 = *(const ushort4*)(h + ((size_t)n4 << 7) + c);
            ushort4 u5 = *(const ushort4*)(h + ((size_t)n5 << 7) + c);
            ushort4 u6 = *(const ushort4*)(h + ((size_t)n6 << 7) + c);
            ushort4 u7 = *(const ushort4*)(h + ((size_t)n7 << 7) + c);
            a0 += bf2f(u0.x) + bf2f(u1.x) + bf2f(u2.x) + bf2f(u3.x)
                + bf2f(u4.x) + bf2f(u5.x) + bf2f(u6.x) + bf2f(u7.x);
            a1 += bf2f(u0.y) + bf2f(u1.y) + bf2f(u2.y) + bf2f(u3.y)
                + bf2f(u4.y) + bf2f(u5.y) + bf2f(u6.y) + bf2f(u7.y);
            a2 += bf2f(u0.z) + bf2f(u1.z) + bf2f(u2.z) + bf2f(u3.z)
                + bf2f(u4.z) + bf2f(u5.z) + bf2f(u6.z) + bf2f(u7.z);
            a3 += bf2f(u0.w) + bf2f(u1.w) + bf2f(u2.w) + bf2f(u3.w)
                + bf2f(u4.w) + bf2f(u5.w) + bf2f(u6.w) + bf2f(u7.w);
        }
        for (; i + 4 <= dd; i += 4) {
            int n0 = ledge[s + i],     n1 = ledge[s + i + 1];
            int n2 = ledge[s + i + 2], n3 = ledge[s + i + 3];
            ushort4 u0 = *(const ushort4*)(h + ((size_t)n0 << 7) + c);
            ushort4 u1 = *(const ushort4*)(h + ((size_t)n1 << 7) + c);
            ushort4 u2 = *(const ushort4*)(h + ((size_t)n2 << 7) + c);
            ushort4 u3 = *(const ushort4*)(h + ((size_t)n3 << 7) + c);
            a0 += bf2f(u0.x) + bf2f(u1.x) + bf2f(u2.x) + bf2f(u3.x);
            a1 += bf2f(u0.y) + bf2f(u1.y) + bf2f(u2.y) + bf2f(u3.y);
            a2 += bf2f(u0.z) + bf2f(u1.z) + bf2f(u2.z) + bf2f(u3.z);
            a3 += bf2f(u0.w) + bf2f(u1.w) + bf2f(u2.w) + bf2f(u3.w);
        }
        for (; i < dd; ++i) {
            int n0 = ledge[s + i];
            ushort4 u0 = *(const ushort4*)(h + ((size_t)n0 << 7) + c);
            a0 += bf2f(u0.x); a1 += bf2f(u0.y); a2 += bf2f(u0.z); a3 += bf2f(u0.w);
        }
        ushort4 r;
        r.x = f2bf(a0); r.y = f2bf(a1); r.z = f2bf(a2); r.w = f2bf(a3);
        *(ushort4*)op = r;
    }
}

// ---------------- GEMM1: A(bf16) @ W + b -> O(bf16) + fused BN stats (fp32) --------
__global__ __launch_bounds__(256, 4) void k_gemm_bf(
        const u16* __restrict__ A, u16* __restrict__ O,
        const float* __restrict__ W, const float* __restrict__ bias,
        float* __restrict__ stats, int M) {
    __shared__ bf16x8 wlds[2048];   // B-frag swizzled, 32 KB
    __shared__ float blds[D], ssum[D], ssq[D];
    int tid = threadIdx.x;
    for (int idx = tid; idx < 2048; idx += 256) {
        int lane_s = idx & 63;
        int f = idx >> 6;
        int n = ((f >> 2) << 4) | (lane_s & 15);
        int kb = ((f & 3) << 5) | ((lane_s >> 4) << 3);
        bf16x8 fr;
#pragma unroll
        for (int j = 0; j < 8; ++j) fr[j] = (__bf16)W[(kb + j) * D + n];
        wlds[idx] = fr;
    }
    if (tid < D) { blds[tid] = bias[tid]; ssum[tid] = 0.f; ssq[tid] = 0.f; }
    __syncthreads();

    int wave = tid >> 6, lane = tid & 63;
    int m = lane & 15, quad = lane >> 4;
    int row0 = blockIdx.x * 64 + wave * 16;

    f32x4 z = {0.f, 0.f, 0.f, 0.f};
    f32x4 acc[8];
#pragma unroll
    for (int t = 0; t < 8; ++t) acc[t] = z;

    const u16* ap = A + (size_t)(row0 + m) * D + (quad << 3);
#pragma unroll
    for (int kc = 0; kc < 4; ++kc) {
        bf16x8 af = *(const bf16x8*)(ap + (kc << 5));
#pragma unroll
        for (int t = 0; t < 8; ++t)
            acc[t] = __builtin_amdgcn_mfma_f32_16x16x32_bf16(
                af, wlds[(((t << 2) | kc) << 6) | lane], acc[t], 0, 0, 0);
    }

    int rbase = row0 + (quad << 2);
#pragma unroll
    for (int t = 0; t < 8; ++t) {
        int cch = (t << 4) | m;
        float bc = blds[cch];
        float s = 0.f, q = 0.f;
#pragma unroll
        for (int r = 0; r < 4; ++r) {
            int row = rbase + r;
            float v = acc[t][r] + bc;
            if (row < M) {
                O[(size_t)row * D + cch] = f2bf(v);
                s += v; q += v * v;
            }
        }
        s += __shfl_xor(s, 16); s += __shfl_xor(s, 32);
        q += __shfl_xor(q, 16); q += __shfl_xor(q, 32);
        if (quad == 0) { atomicAdd(&ssum[cch], s); atomicAdd(&ssq[cch], q); }
    }
    __syncthreads();
    if (tid < D) {
        atomicAdd(&stats[tid], ssum[tid]);
        atomicAdd(&stats[D + tid], ssq[tid]);
    }
}

// ---------------- GEMM2: A(bf16) -> BN1+ReLU on the fly -> @W + b, in-place, +stats2
__global__ __launch_bounds__(256, 4) void k_gemm_bn(
        u16* __restrict__ A, const float* __restrict__ W,
        const float* __restrict__ bias, const float* __restrict__ stats_in,
        const float* __restrict__ gamma, const float* __restrict__ beta,
        float* __restrict__ stats_out, float invM, int M) {
    __shared__ bf16x8 wlds[2048];
    __shared__ float blds[D], s_sc[D], s_sh[D], ssum[D], ssq[D];
    int tid = threadIdx.x;
    for (int idx = tid; idx < 2048; idx += 256) {
        int lane_s = idx & 63;
        int f = idx >> 6;
        int n = ((f >> 2) << 4) | (lane_s & 15);
        int kb = ((f & 3) << 5) | ((lane_s >> 4) << 3);
        bf16x8 fr;
#pragma unroll
        for (int j = 0; j < 8; ++j) fr[j] = (__bf16)W[(kb + j) * D + n];
        wlds[idx] = fr;
    }
    if (tid < D) {
        float mean = stats_in[tid] * invM;
        float var = stats_in[D + tid] * invM - mean * mean;
        float sc = rsqrtf(var + 1e-5f) * gamma[tid];
        s_sc[tid] = sc;
        s_sh[tid] = beta[tid] - mean * sc;
        blds[tid] = bias[tid];
        ssum[tid] = 0.f; ssq[tid] = 0.f;
    }
    __syncthreads();

    int wave = tid >> 6, lane = tid & 63;
    int m = lane & 15, quad = lane >> 4;
    int row0 = blockIdx.x * 64 + wave * 16;

    f32x4 z = {0.f, 0.f, 0.f, 0.f};
    f32x4 acc[8];
#pragma unroll
    for (int t = 0; t < 8; ++t) acc[t] = z;

    const u16* ap = A + (size_t)(row0 + m) * D + (quad << 3);
#pragma unroll
    for (int kc = 0; kc < 4; ++kc) {
        int kb = (kc << 5) | (quad << 3);
        ushort4 p0 = *(const ushort4*)(ap + (kc << 5));
        ushort4 p1 = *(const ushort4*)(ap + (kc << 5) + 4);
        float4 c0 = *(const float4*)&s_sc[kb];
        float4 c1 = *(const float4*)&s_sc[kb + 4];
        float4 h0 = *(const float4*)&s_sh[kb];
        float4 h1 = *(const float4*)&s_sh[kb + 4];
        bf16x8 af;
        af[0] = (__bf16)fmaxf(0.f, fmaf(bf2f(p0.x), c0.x, h0.x));
        af[1] = (__bf16)fmaxf(0.f, fmaf(bf2f(p0.y), c0.y, h0.y));
        af[2] = (__bf16)fmaxf(0.f, fmaf(bf2f(p0.z), c0.z, h0.z));
        af[3] = (__bf16)fmaxf(0.f, fmaf(bf2f(p0.w), c0.w, h0.w));
        af[4] = (__bf16)fmaxf(0.f, fmaf(bf2f(p1.x), c1.x, h1.x));
        af[5] = (__bf16)fmaxf(0.f, fmaf(bf2f(p1.y), c1.y, h1.y));
        af[6] = (__bf16)fmaxf(0.f, fmaf(bf2f(p1.z), c1.z, h1.z));
        af[7] = (__bf16)fmaxf(0.f, fmaf(bf2f(p1.w), c1.w, h1.w));
#pragma unroll
        for (int t = 0; t < 8; ++t)
            acc[t] = __builtin_amdgcn_mfma_f32_16x16x32_bf16(
                af, wlds[(((t << 2) | kc) << 6) | lane], acc[t], 0, 0, 0);
    }

    int rbase = row0 + (quad << 2);
#pragma unroll
    for (int t = 0; t < 8; ++t) {
        int cch = (t << 4) | m;
        float bc = blds[cch];
        float s = 0.f, q = 0.f;
#pragma unroll
        for (int r = 0; r < 4; ++r) {
            int row = rbase + r;
            float v = acc[t][r] + bc;
            if (row < M) {
                A[(size_t)row * D + cch] = f2bf(v);
                s += v; q += v * v;
            }
        }
        s += __shfl_xor(s, 16); s += __shfl_xor(s, 32);
        q += __shfl_xor(q, 16); q += __shfl_xor(q, 32);
        if (quad == 0) { atomicAdd(&ssum[cch], s); atomicAdd(&ssq[cch], q); }
    }
    __syncthreads();
    if (tid < D) {
        atomicAdd(&stats_out[tid], ssum[tid]);
        atomicAdd(&stats_out[D + tid], ssq[tid]);
    }
}

// ---------------- BN2 + ReLU -> bf16 h, + fused weighted graph pooling ----------------
// 256 thr: 8 strips x 8 rows; lane handles 4 channels (ushort4)
__global__ __launch_bounds__(256) void k_bn2pool(
        const u16* __restrict__ y, const float* __restrict__ stats,
        const float* __restrict__ gamma, const float* __restrict__ beta,
        const int* __restrict__ gids, const float* __restrict__ fw,
        int layer, u16* __restrict__ hout, float* __restrict__ gacc,
        float invM, int M) {
    int t = threadIdx.x;
    int c = (t & 31) << 2;
    int strip = t >> 5;
    long base = (long)blockIdx.x * 64 + (long)strip * 8;
    if (base >= M) return;
    long nend = base + 8; if (nend > M) nend = M;
    float sc[4], sh[4];
#pragma unroll
    for (int j = 0; j < 4; ++j) {
        float mean = stats[c + j] * invM;
        float s = rsqrtf(stats[D + c + j] * invM - mean * mean + 1e-5f) * gamma[c + j];
        sc[j] = s;
        sh[j] = beta[c + j] - mean * s;
    }
    float wl = fw[layer];
    int cur = -1;
    float a0 = 0.f, a1 = 0.f, a2 = 0.f, a3 = 0.f;
    for (long node = base; node < nend; ++node) {
        ushort4 v = *(const ushort4*)(y + (node << 7) + c);
        float h0 = fmaxf(0.f, fmaf(bf2f(v.x), sc[0], sh[0]));
        float h1 = fmaxf(0.f, fmaf(bf2f(v.y), sc[1], sh[1]));
        float h2 = fmaxf(0.f, fmaf(bf2f(v.z), sc[2], sh[2]));
        float h3 = fmaxf(0.f, fmaf(bf2f(v.w), sc[3], sh[3]));
        ushort4 r;
        r.x = f2bf(h0); r.y = f2bf(h1); r.z = f2bf(h2); r.w = f2bf(h3);
        *(ushort4*)(hout + (node << 7) + c) = r;
        int gid = gids[node];
        if (gid != cur) {
            if (cur >= 0) {
                float* gp = gacc + ((size_t)cur << 7) + c;
                atomicAdd(gp, wl * a0); atomicAdd(gp + 1, wl * a1);
                atomicAdd(gp + 2, wl * a2); atomicAdd(gp + 3, wl * a3);
            }
            cur = gid;
            a0 = a1 = a2 = a3 = 0.f;
        }
        a0 += h0; a1 += h1; a2 += h2; a3 += h3;
    }
    if (cur >= 0) {
        float* gp = gacc + ((size_t)cur << 7) + c;
        atomicAdd(gp, wl * a0); atomicAdd(gp + 1, wl * a1);
        atomicAdd(gp + 2, wl * a2); atomicAdd(gp + 3, wl * a3);
    }
}

// ---------------- final: out = gacc(Gx128) @ Wp(128x10) + bp ----------------
__global__ void k_final(const float* __restrict__ gacc, const float* __restrict__ Wp,
                        const float* __restrict__ bp, float* __restrict__ out) {
    __shared__ float w[D * DOUT];
    __shared__ float bb[DOUT];
    int t = threadIdx.x;
    for (int i = t; i < D * DOUT; i += blockDim.x) w[i] = Wp[i];
    if (t < DOUT) bb[t] = bp[t];
    __syncthreads();
    float acc[DOUT];
#pragma unroll
    for (int o = 0; o < DOUT; ++o) acc[o] = bb[o];
    for (int k = 0; k < D; ++k) {
        float a = gacc[(size_t)t * D + k];
#pragma unroll
        for (int o = 0; o < DOUT; ++o) acc[o] += a * w[k * DOUT + o];
    }
#pragma unroll
    for (int o = 0; o < DOUT; ++o) out[(size_t)t * DOUT + o] = acc[o];
}

extern "C" void kernel_launch(void* const* d_in, const int* in_sizes, int n_in,
                              void* d_out, int out_size, void* d_ws, size_t ws_size,
                              hipStream_t stream) {
    const float* x    = (const float*)d_in[0];
    const int* esrc   = (const int*)d_in[1];
    const int* edst   = (const int*)d_in[2];
    const int* gids   = (const int*)d_in[3];
    const float* eps  = (const float*)d_in[4];
    const float* fw   = (const float*)d_in[5];
    const float* W1   = (const float*)d_in[6];
    const float* b1   = (const float*)d_in[7];
    const float* g1   = (const float*)d_in[8];
    const float* bt1  = (const float*)d_in[9];
    const float* W2   = (const float*)d_in[10];
    const float* b2   = (const float*)d_in[11];
    const float* g2   = (const float*)d_in[12];
    const float* bt2  = (const float*)d_in[13];
    const float* Wp   = (const float*)d_in[14];
    const float* bp   = (const float*)d_in[15];
    float* out        = (float*)d_out;

    const int M = in_sizes[3];     // 100000 nodes
    const int E = in_sizes[1];     // 1600000 edges
    const int L = in_sizes[4];     // 4 layers
    const int G = out_size / DOUT; // 256 graphs
    const int Mpad = ((M + 63) / 64) * 64;
    const int nb  = (M + 127) >> 7;           // buckets of 128 dst nodes (782)
    const int nbk = (E + 16383) >> 14;        // 16K-edge chunks (98)
    const float invM = 1.0f / (float)M;

    char* ws = (char*)d_ws;
    u16* bufP  = (u16*)ws;  ws += (size_t)Mpad * D * 2;   // pooled bf16
    u16* bufT  = (u16*)ws;  ws += (size_t)Mpad * D * 2;   // MLP temp bf16
    u16* bufH  = (u16*)ws;  ws += (size_t)Mpad * D * 2;   // hidden bf16
    int* pairs = (int*)ws;  ws += (size_t)nb * 4096 * 4;  // packed (src<<7)|(dst&127)
    int* cnts  = (int*)ws;  ws += (size_t)nbk * 1024 * 4; // per-(chunk,bucket) counts/bases
    int* btot  = (int*)ws;  ws += 1024 * 4;               // bucket totals
    // contiguous zero region: stats | gacc
    float* stats = (float*)ws; ws += (size_t)L * 512 * 4;
    float* gacc  = (float*)ws; ws += (size_t)G * D * 4;

    int zbytes = L * 512 * 4 + G * D * 4;
    int n4 = zbytes / 16;
    k_zero<<<(n4 + 255) / 256, 256, 0, stream>>>((float4*)stats, n4);

    k_hist<<<nbk, 256, 0, stream>>>(edst, cnts, E, nb);
    k_off<<<(nb + 255) / 256, 256, 0, stream>>>(cnts, btot, nbk, nb);
    k_scat<<<nbk, 256, 0, stream>>>(esrc, edst, cnts, pairs, E, nb);
    k_cvt<<<(Mpad * (D / 4) + 255) / 256, 256, 0, stream>>>(x, bufH, M, Mpad);

    int gemm_grid = Mpad / 64;
    int pool_grid = (M + 63) / 64;
    for (int l = 0; l < L; ++l) {
        float* st1 = stats + (size_t)l * 512;
        float* st2 = st1 + 256;
        k_agg<<<nb, 512, 0, stream>>>(bufH, pairs, btot, eps, l, bufP, M, Mpad);
        k_gemm_bf<<<gemm_grid, 256, 0, stream>>>(bufP, bufT, W1 + (size_t)l * D * D,
                                                 b1 + (size_t)l * D, st1, M);
        k_gemm_bn<<<gemm_grid, 256, 0, stream>>>(bufT, W2 + (size_t)l * D * D,
                                                 b2 + (size_t)l * D, st1,
                                                 g1 + (size_t)l * D, bt1 + (size_t)l * D,
                                                 st2, invM, M);
        k_bn2pool<<<pool_grid, 256, 0, stream>>>(bufT, st2, g2 + (size_t)l * D,
                                                 bt2 + (size_t)l * D, gids, fw, l,
                                                 bufH, gacc, invM, M);
    }
    k_final<<<1, G, 0, stream>>>(gacc, Wp, bp, out);
}

// Round 6
// 928.137 us; speedup vs baseline: 6.8216x; 1.1640x over previous
//
#include <hip/hip_runtime.h>

#define D 128            // hidden dim
#define DOUT 10

typedef float f32x4 __attribute__((ext_vector_type(4)));
typedef __bf16 bf16x8 __attribute__((ext_vector_type(8)));
typedef unsigned short u16;

__device__ __forceinline__ float bf2f(u16 u) {
    return __uint_as_float(((unsigned int)u) << 16);
}
__device__ __forceinline__ u16 f2bf(float f) {
    unsigned int u = __float_as_uint(f);
    u += 0x7fffu + ((u >> 16) & 1u);
    return (u16)(u >> 16);
}

// ---------------- zero init (stats | gacc contiguous) ----------------
__global__ void k_zero(float4* __restrict__ p, int n4) {
    int i = blockIdx.x * 256 + threadIdx.x;
    if (i < n4) p[i] = make_float4(0.f, 0.f, 0.f, 0.f);
}

// ---------------- pre-swizzle W1/W2 into MFMA B-fragment order (once per call) -----
// frag f = ntile*4+kc, lane: n=((f>>2)<<4)|(lane&15), k=((f&3)<<5)|((lane>>4)<<3)+j
__global__ __launch_bounds__(256) void k_prepw(const float* __restrict__ W1,
                                               const float* __restrict__ W2,
                                               bf16x8* __restrict__ wswz, int L) {
    int b = blockIdx.x;
    const float* W = (b < L) ? (W1 + (size_t)b * D * D)
                             : (W2 + (size_t)(b - L) * D * D);
    bf16x8* o = wswz + (size_t)b * 2048;
    int tid = threadIdx.x;
    for (int idx = tid; idx < 2048; idx += 256) {
        int lane_s = idx & 63;
        int f = idx >> 6;
        int n = ((f >> 2) << 4) | (lane_s & 15);
        int kb = ((f & 3) << 5) | ((lane_s >> 4) << 3);
        bf16x8 fr;
#pragma unroll
        for (int j = 0; j < 8; ++j) fr[j] = (__bf16)W[(kb + j) * D + n];
        o[idx] = fr;
    }
}

// ============ bucketing: deterministic two-level, NO contended global atomics ======
__global__ __launch_bounds__(256) void k_hist(const int* __restrict__ dst,
                                              int* __restrict__ cnts, int E, int nb) {
    __shared__ int hist[1024];
    int tid = threadIdx.x;
    for (int i = tid; i < nb; i += 256) hist[i] = 0;
    __syncthreads();
    int e0 = blockIdx.x << 14;
    int e1 = e0 + 16384; if (e1 > E) e1 = E;
    for (int e = e0 + tid; e < e1; e += 256) atomicAdd(&hist[dst[e] >> 7], 1);
    __syncthreads();
    for (int i = tid; i < nb; i += 256) cnts[(blockIdx.x << 10) + i] = hist[i];
}

__global__ void k_off(int* __restrict__ cnts, int* __restrict__ btot, int nbk, int nb) {
    int b = blockIdx.x * 256 + threadIdx.x;
    if (b >= nb) return;
    int run = 0;
    for (int k = 0; k < nbk; ++k) {
        int idx = (k << 10) + b;
        int c = cnts[idx];
        cnts[idx] = run;
        run += c;
    }
    btot[b] = run;
}

__global__ __launch_bounds__(256) void k_scat(const int* __restrict__ src,
                                              const int* __restrict__ dst,
                                              const int* __restrict__ cnts,
                                              int* __restrict__ pairs, int E, int nb) {
    __shared__ int lbase[1024];
    __shared__ int lcur[1024];
    int tid = threadIdx.x;
    for (int i = tid; i < nb; i += 256) {
        lbase[i] = cnts[(blockIdx.x << 10) + i];
        lcur[i] = 0;
    }
    __syncthreads();
    int e0 = blockIdx.x << 14;
    int e1 = e0 + 16384; if (e1 > E) e1 = E;
    for (int e = e0 + tid; e < e1; e += 256) {
        int d = dst[e];
        int b = d >> 7;
        int pos = lbase[b] + atomicAdd(&lcur[b], 1);
        if (pos < 4096) pairs[(b << 12) + pos] = (src[e] << 7) | (d & 127);
    }
}

// ---------------- x fp32 -> bf16 (padded rows zeroed) ----------------
__global__ void k_cvt(const float* __restrict__ x, u16* __restrict__ o,
                      int M, int Mpad) {
    long e = ((long)blockIdx.x * 256 + threadIdx.x) * 4;
    if (e >= (long)Mpad * D) return;
    ushort4 r;
    if (e < (long)M * D) {
        float4 v = *(const float4*)(x + e);
        r.x = f2bf(v.x); r.y = f2bf(v.y); r.z = f2bf(v.z); r.w = f2bf(v.w);
    } else {
        r = make_ushort4(0, 0, 0, 0);
    }
    *(ushort4*)(o + e) = r;
}

// ---------------- bucket aggregation: local CSR in LDS, register accumulation -----
__global__ __launch_bounds__(512) void k_agg(
        const u16* __restrict__ h, const int* __restrict__ pairs,
        const int* __restrict__ bcnt, const float* __restrict__ eps, int layer,
        u16* __restrict__ out, int M, int Mpad) {
    __shared__ int lcnt[128];
    __shared__ int loff[128];
    __shared__ int lcur[128];
    __shared__ int ledge[4096];
    int tid = threadIdx.x;
    if (tid < 128) lcnt[tid] = 0;
    __syncthreads();

    int b = blockIdx.x;
    int cnt = bcnt[b];
    if (cnt > 4096) cnt = 4096;
    const int* pb = pairs + ((size_t)b << 12);

    for (int e = tid; e < cnt; e += 512)
        atomicAdd(&lcnt[pb[e] & 127], 1);
    __syncthreads();

    if (tid < 128) loff[tid] = lcnt[tid];
    __syncthreads();
    for (int off = 1; off < 128; off <<= 1) {
        int v = 0;
        if (tid < 128 && tid >= off) v = loff[tid - off];
        __syncthreads();
        if (tid < 128) loff[tid] += v;
        __syncthreads();
    }
    if (tid < 128) lcur[tid] = loff[tid] - lcnt[tid];
    __syncthreads();

    for (int e = tid; e < cnt; e += 512) {
        int p = pb[e];
        int pos = atomicAdd(&lcur[p & 127], 1);
        ledge[pos] = p >> 7;
    }
    __syncthreads();

    float e1 = 1.0f + eps[layer];
    int grp = tid >> 5;
    int c = (tid & 31) << 2;
    for (int pass = 0; pass < 8; ++pass) {
        int row = (pass << 4) + grp;
        int node = (b << 7) + row;
        if (node >= Mpad) continue;
        u16* op = out + ((size_t)node << 7) + c;
        if (node >= M) { *(ushort4*)op = make_ushort4(0, 0, 0, 0); continue; }
        ushort4 sv = *(const ushort4*)(h + ((size_t)node << 7) + c);
        float a0 = e1 * bf2f(sv.x), a1 = e1 * bf2f(sv.y);
        float a2 = e1 * bf2f(sv.z), a3 = e1 * bf2f(sv.w);
        int dd = lcnt[row];
        int s = loff[row] - dd;
        int i = 0;
        for (; i + 8 <= dd; i += 8) {
            int n0 = ledge[s + i],     n1 = ledge[s + i + 1];
            int n2 = ledge[s + i + 2], n3 = ledge[s + i + 3];
            int n4 = ledge[s + i + 4], n5 = ledge[s + i + 5];
            int n6 = ledge[s + i + 6], n7 = ledge[s + i + 7];
            ushort4 u0 = *(const ushort4*)(h + ((size_t)n0 << 7) + c);
            ushort4 u1 = *(const ushort4*)(h + ((size_t)n1 << 7) + c);
            ushort4 u2 = *(const ushort4*)(h + ((size_t)n2 << 7) + c);
            ushort4 u3 = *(const ushort4*)(h + ((size_t)n3 << 7) + c);
            ushort4 u4 = *(const ushort4*)(h + ((size_t)n4 << 7) + c);
            ushort4 u5 = *(const ushort4*)(h + ((size_t)n5 << 7) + c);
            ushort4 u6 = *(const ushort4*)(h + ((size_t)n6 << 7) + c);
            ushort4 u7 = *(const ushort4*)(h + ((size_t)n7 << 7) + c);
            a0 += bf2f(u0.x) + bf2f(u1.x) + bf2f(u2.x) + bf2f(u3.x)
                + bf2f(u4.x) + bf2f(u5.x) + bf2f(u6.x) + bf2f(u7.x);
            a1 += bf2f(u0.y) + bf2f(u1.y) + bf2f(u2.y) + bf2f(u3.y)
                + bf2f(u4.y) + bf2f(u5.y) + bf2f(u6.y) + bf2f(u7.y);
            a2 += bf2f(u0.z) + bf2f(u1.z) + bf2f(u2.z) + bf2f(u3.z)
                + bf2f(u4.z) + bf2f(u5.z) + bf2f(u6.z) + bf2f(u7.z);
            a3 += bf2f(u0.w) + bf2f(u1.w) + bf2f(u2.w) + bf2f(u3.w)
                + bf2f(u4.w) + bf2f(u5.w) + bf2f(u6.w) + bf2f(u7.w);
        }
        for (; i + 4 <= dd; i += 4) {
            int n0 = ledge[s + i],     n1 = ledge[s + i + 1];
            int n2 = ledge[s + i + 2], n3 = ledge[s + i + 3];
            ushort4 u0 = *(const ushort4*)(h + ((size_t)n0 << 7) + c);
            ushort4 u1 = *(const ushort4*)(h + ((size_t)n1 << 7) + c);
            ushort4 u2 = *(const ushort4*)(h + ((size_t)n2 << 7) + c);
            ushort4 u3 = *(const ushort4*)(h + ((size_t)n3 << 7) + c);
            a0 += bf2f(u0.x) + bf2f(u1.x) + bf2f(u2.x) + bf2f(u3.x);
            a1 += bf2f(u0.y) + bf2f(u1.y) + bf2f(u2.y) + bf2f(u3.y);
            a2 += bf2f(u0.z) + bf2f(u1.z) + bf2f(u2.z) + bf2f(u3.z);
            a3 += bf2f(u0.w) + bf2f(u1.w) + bf2f(u2.w) + bf2f(u3.w);
        }
        for (; i < dd; ++i) {
            int n0 = ledge[s + i];
            ushort4 u0 = *(const ushort4*)(h + ((size_t)n0 << 7) + c);
            a0 += bf2f(u0.x); a1 += bf2f(u0.y); a2 += bf2f(u0.z); a3 += bf2f(u0.w);
        }
        ushort4 r;
        r.x = f2bf(a0); r.y = f2bf(a1); r.z = f2bf(a2); r.w = f2bf(a3);
        *(ushort4*)op = r;
    }
}

// ---------------- GEMM1: A(bf16) @ W + b -> O(bf16) + fused BN stats ---------------
// 128-row tile, 256 thr = 4 waves, 2 row-tiles per wave; W pre-swizzled (pure copy).
__global__ __launch_bounds__(256, 3) void k_gemm_bf(
        const u16* __restrict__ A, u16* __restrict__ O,
        const bf16x8* __restrict__ wz, const float* __restrict__ bias,
        float* __restrict__ stats, int M) {
    __shared__ bf16x8 wlds[2048];   // 32 KB, fragment order
    __shared__ float blds[D], ssum[D], ssq[D];
    int tid = threadIdx.x;
    for (int i = tid; i < 2048; i += 256) wlds[i] = wz[i];
    if (tid < D) { blds[tid] = bias[tid]; ssum[tid] = 0.f; ssq[tid] = 0.f; }
    __syncthreads();

    int wave = tid >> 6, lane = tid & 63;
    int m = lane & 15, quad = lane >> 4;
    int row0 = blockIdx.x * 128 + wave * 32;

    f32x4 z = {0.f, 0.f, 0.f, 0.f};
    f32x4 acc0[8], acc1[8];
#pragma unroll
    for (int t = 0; t < 8; ++t) { acc0[t] = z; acc1[t] = z; }

    const u16* ap0 = A + (size_t)(row0 + m) * D + (quad << 3);
    const u16* ap1 = ap0 + (size_t)16 * D;
#pragma unroll
    for (int kc = 0; kc < 4; ++kc) {
        bf16x8 af0 = *(const bf16x8*)(ap0 + (kc << 5));
        bf16x8 af1 = *(const bf16x8*)(ap1 + (kc << 5));
#pragma unroll
        for (int t = 0; t < 8; ++t) {
            bf16x8 bf = wlds[(((t << 2) | kc) << 6) | lane];
            acc0[t] = __builtin_amdgcn_mfma_f32_16x16x32_bf16(af0, bf, acc0[t], 0, 0, 0);
            acc1[t] = __builtin_amdgcn_mfma_f32_16x16x32_bf16(af1, bf, acc1[t], 0, 0, 0);
        }
    }

    int rb0 = row0 + (quad << 2);
    int rb1 = rb0 + 16;
#pragma unroll
    for (int t = 0; t < 8; ++t) {
        int cch = (t << 4) | m;
        float bc = blds[cch];
        float s = 0.f, q = 0.f;
#pragma unroll
        for (int r = 0; r < 4; ++r) {
            int row = rb0 + r;
            float v = acc0[t][r] + bc;
            if (row < M) { O[(size_t)row * D + cch] = f2bf(v); s += v; q += v * v; }
        }
#pragma unroll
        for (int r = 0; r < 4; ++r) {
            int row = rb1 + r;
            float v = acc1[t][r] + bc;
            if (row < M) { O[(size_t)row * D + cch] = f2bf(v); s += v; q += v * v; }
        }
        s += __shfl_xor(s, 16); s += __shfl_xor(s, 32);
        q += __shfl_xor(q, 16); q += __shfl_xor(q, 32);
        if (quad == 0) { atomicAdd(&ssum[cch], s); atomicAdd(&ssq[cch], q); }
    }
    __syncthreads();
    if (tid < D) {
        atomicAdd(&stats[tid], ssum[tid]);
        atomicAdd(&stats[D + tid], ssq[tid]);
    }
}

// ---------------- GEMM2: A(bf16) -> BN1+ReLU on the fly -> @W + b, in-place, +stats2
__global__ __launch_bounds__(256, 3) void k_gemm_bn(
        u16* __restrict__ A, const bf16x8* __restrict__ wz,
        const float* __restrict__ bias, const float* __restrict__ stats_in,
        const float* __restrict__ gamma, const float* __restrict__ beta,
        float* __restrict__ stats_out, float invM, int M) {
    __shared__ bf16x8 wlds[2048];
    __shared__ float blds[D], s_sc[D], s_sh[D], ssum[D], ssq[D];
    int tid = threadIdx.x;
    for (int i = tid; i < 2048; i += 256) wlds[i] = wz[i];
    if (tid < D) {
        float mean = stats_in[tid] * invM;
        float var = stats_in[D + tid] * invM - mean * mean;
        float sc = rsqrtf(var + 1e-5f) * gamma[tid];
        s_sc[tid] = sc;
        s_sh[tid] = beta[tid] - mean * sc;
        blds[tid] = bias[tid];
        ssum[tid] = 0.f; ssq[tid] = 0.f;
    }
    __syncthreads();

    int wave = tid >> 6, lane = tid & 63;
    int m = lane & 15, quad = lane >> 4;
    int row0 = blockIdx.x * 128 + wave * 32;

    f32x4 z = {0.f, 0.f, 0.f, 0.f};
    f32x4 acc0[8], acc1[8];
#pragma unroll
    for (int t = 0; t < 8; ++t) { acc0[t] = z; acc1[t] = z; }

    const u16* ap0 = A + (size_t)(row0 + m) * D + (quad << 3);
    const u16* ap1 = ap0 + (size_t)16 * D;
#pragma unroll
    for (int kc = 0; kc < 4; ++kc) {
        int kb = (kc << 5) | (quad << 3);
        float4 c0 = *(const float4*)&s_sc[kb];
        float4 c1 = *(const float4*)&s_sc[kb + 4];
        float4 h0 = *(const float4*)&s_sh[kb];
        float4 h1 = *(const float4*)&s_sh[kb + 4];
        ushort4 p0 = *(const ushort4*)(ap0 + (kc << 5));
        ushort4 p1 = *(const ushort4*)(ap0 + (kc << 5) + 4);
        ushort4 q0 = *(const ushort4*)(ap1 + (kc << 5));
        ushort4 q1 = *(const ushort4*)(ap1 + (kc << 5) + 4);
        bf16x8 af0, af1;
        af0[0] = (__bf16)fmaxf(0.f, fmaf(bf2f(p0.x), c0.x, h0.x));
        af0[1] = (__bf16)fmaxf(0.f, fmaf(bf2f(p0.y), c0.y, h0.y));
        af0[2] = (__bf16)fmaxf(0.f, fmaf(bf2f(p0.z), c0.z, h0.z));
        af0[3] = (__bf16)fmaxf(0.f, fmaf(bf2f(p0.w), c0.w, h0.w));
        af0[4] = (__bf16)fmaxf(0.f, fmaf(bf2f(p1.x), c1.x, h1.x));
        af0[5] = (__bf16)fmaxf(0.f, fmaf(bf2f(p1.y), c1.y, h1.y));
        af0[6] = (__bf16)fmaxf(0.f, fmaf(bf2f(p1.z), c1.z, h1.z));
        af0[7] = (__bf16)fmaxf(0.f, fmaf(bf2f(p1.w), c1.w, h1.w));
        af1[0] = (__bf16)fmaxf(0.f, fmaf(bf2f(q0.x), c0.x, h0.x));
        af1[1] = (__bf16)fmaxf(0.f, fmaf(bf2f(q0.y), c0.y, h0.y));
        af1[2] = (__bf16)fmaxf(0.f, fmaf(bf2f(q0.z), c0.z, h0.z));
        af1[3] = (__bf16)fmaxf(0.f, fmaf(bf2f(q0.w), c0.w, h0.w));
        af1[4] = (__bf16)fmaxf(0.f, fmaf(bf2f(q1.x), c1.x, h1.x));
        af1[5] = (__bf16)fmaxf(0.f, fmaf(bf2f(q1.y), c1.y, h1.y));
        af1[6] = (__bf16)fmaxf(0.f, fmaf(bf2f(q1.z), c1.z, h1.z));
        af1[7] = (__bf16)fmaxf(0.f, fmaf(bf2f(q1.w), c1.w, h1.w));
#pragma unroll
        for (int t = 0; t < 8; ++t) {
            bf16x8 bf = wlds[(((t << 2) | kc) << 6) | lane];
            acc0[t] = __builtin_amdgcn_mfma_f32_16x16x32_bf16(af0, bf, acc0[t], 0, 0, 0);
            acc1[t] = __builtin_amdgcn_mfma_f32_16x16x32_bf16(af1, bf, acc1[t], 0, 0, 0);
        }
    }

    int rb0 = row0 + (quad << 2);
    int rb1 = rb0 + 16;
#pragma unroll
    for (int t = 0; t < 8; ++t) {
        int cch = (t << 4) | m;
        float bc = blds[cch];
        float s = 0.f, q = 0.f;
#pragma unroll
        for (int r = 0; r < 4; ++r) {
            int row = rb0 + r;
            float v = acc0[t][r] + bc;
            if (row < M) { A[(size_t)row * D + cch] = f2bf(v); s += v; q += v * v; }
        }
#pragma unroll
        for (int r = 0; r < 4; ++r) {
            int row = rb1 + r;
            float v = acc1[t][r] + bc;
            if (row < M) { A[(size_t)row * D + cch] = f2bf(v); s += v; q += v * v; }
        }
        s += __shfl_xor(s, 16); s += __shfl_xor(s, 32);
        q += __shfl_xor(q, 16); q += __shfl_xor(q, 32);
        if (quad == 0) { atomicAdd(&ssum[cch], s); atomicAdd(&ssq[cch], q); }
    }
    __syncthreads();
    if (tid < D) {
        atomicAdd(&stats_out[tid], ssum[tid]);
        atomicAdd(&stats_out[D + tid], ssq[tid]);
    }
}

// ---------------- BN2 + ReLU -> bf16 h, + fused weighted graph pooling -------------
__global__ __launch_bounds__(256) void k_bn2pool(
        const u16* __restrict__ y, const float* __restrict__ stats,
        const float* __restrict__ gamma, const float* __restrict__ beta,
        const int* __restrict__ gids, const float* __restrict__ fw,
        int layer, u16* __restrict__ hout, float* __restrict__ gacc,
        float invM, int M) {
    int t = threadIdx.x;
    int c = (t & 31) << 2;
    int strip = t >> 5;
    long base = (long)blockIdx.x * 64 + (long)strip * 8;
    if (base >= M) return;
    long nend = base + 8; if (nend > M) nend = M;
    float sc[4], sh[4];
#pragma unroll
    for (int j = 0; j < 4; ++j) {
        float mean = stats[c + j] * invM;
        float s = rsqrtf(stats[D + c + j] * invM - mean * mean + 1e-5f) * gamma[c + j];
        sc[j] = s;
        sh[j] = beta[c + j] - mean * s;
    }
    float wl = fw[layer];
    int cur = -1;
    float a0 = 0.f, a1 = 0.f, a2 = 0.f, a3 = 0.f;
    for (long node = base; node < nend; ++node) {
        ushort4 v = *(const ushort4*)(y + (node << 7) + c);
        float h0 = fmaxf(0.f, fmaf(bf2f(v.x), sc[0], sh[0]));
        float h1 = fmaxf(0.f, fmaf(bf2f(v.y), sc[1], sh[1]));
        float h2 = fmaxf(0.f, fmaf(bf2f(v.z), sc[2], sh[2]));
        float h3 = fmaxf(0.f, fmaf(bf2f(v.w), sc[3], sh[3]));
        ushort4 r;
        r.x = f2bf(h0); r.y = f2bf(h1); r.z = f2bf(h2); r.w = f2bf(h3);
        *(ushort4*)(hout + (node << 7) + c) = r;
        int gid = gids[node];
        if (gid != cur) {
            if (cur >= 0) {
                float* gp = gacc + ((size_t)cur << 7) + c;
                atomicAdd(gp, wl * a0); atomicAdd(gp + 1, wl * a1);
                atomicAdd(gp + 2, wl * a2); atomicAdd(gp + 3, wl * a3);
            }
            cur = gid;
            a0 = a1 = a2 = a3 = 0.f;
        }
        a0 += h0; a1 += h1; a2 += h2; a3 += h3;
    }
    if (cur >= 0) {
        float* gp = gacc + ((size_t)cur << 7) + c;
        atomicAdd(gp, wl * a0); atomicAdd(gp + 1, wl * a1);
        atomicAdd(gp + 2, wl * a2); atomicAdd(gp + 3, wl * a3);
    }
}

// ---------------- final: out = gacc(Gx128) @ Wp(128x10) + bp ----------------
__global__ void k_final(const float* __restrict__ gacc, const float* __restrict__ Wp,
                        const float* __restrict__ bp, float* __restrict__ out) {
    __shared__ float w[D * DOUT];
    __shared__ float bb[DOUT];
    int t = threadIdx.x;
    for (int i = t; i < D * DOUT; i += blockDim.x) w[i] = Wp[i];
    if (t < DOUT) bb[t] = bp[t];
    __syncthreads();
    float acc[DOUT];
#pragma unroll
    for (int o = 0; o < DOUT; ++o) acc[o] = bb[o];
    for (int k = 0; k < D; ++k) {
        float a = gacc[(size_t)t * D + k];
#pragma unroll
        for (int o = 0; o < DOUT; ++o) acc[o] += a * w[k * DOUT + o];
    }
#pragma unroll
    for (int o = 0; o < DOUT; ++o) out[(size_t)t * DOUT + o] = acc[o];
}

extern "C" void kernel_launch(void* const* d_in, const int* in_sizes, int n_in,
                              void* d_out, int out_size, void* d_ws, size_t ws_size,
                              hipStream_t stream) {
    const float* x    = (const float*)d_in[0];
    const int* esrc   = (const int*)d_in[1];
    const int* edst   = (const int*)d_in[2];
    const int* gids   = (const int*)d_in[3];
    const float* eps  = (const float*)d_in[4];
    const float* fw   = (const float*)d_in[5];
    const float* W1   = (const float*)d_in[6];
    const float* b1   = (const float*)d_in[7];
    const float* g1   = (const float*)d_in[8];
    const float* bt1  = (const float*)d_in[9];
    const float* W2   = (const float*)d_in[10];
    const float* b2   = (const float*)d_in[11];
    const float* g2   = (const float*)d_in[12];
    const float* bt2  = (const float*)d_in[13];
    const float* Wp   = (const float*)d_in[14];
    const float* bp   = (const float*)d_in[15];
    float* out        = (float*)d_out;

    const int M = in_sizes[3];     // 100000 nodes
    const int E = in_sizes[1];     // 1600000 edges
    const int L = in_sizes[4];     // 4 layers
    const int G = out_size / DOUT; // 256 graphs
    const int nb  = (M + 127) >> 7;           // buckets of 128 dst nodes (782)
    const int Mpad = nb << 7;                 // multiple of 128, == bucket coverage
    const int nbk = (E + 16383) >> 14;        // 16K-edge chunks (98)
    const float invM = 1.0f / (float)M;

    char* ws = (char*)d_ws;
    u16* bufP  = (u16*)ws;  ws += (size_t)Mpad * D * 2;   // pooled bf16
    u16* bufT  = (u16*)ws;  ws += (size_t)Mpad * D * 2;   // MLP temp bf16
    u16* bufH  = (u16*)ws;  ws += (size_t)Mpad * D * 2;   // hidden bf16
    int* pairs = (int*)ws;  ws += (size_t)nb * 4096 * 4;  // packed (src<<7)|(dst&127)
    int* cnts  = (int*)ws;  ws += (size_t)nbk * 1024 * 4; // per-(chunk,bucket) bases
    int* btot  = (int*)ws;  ws += 1024 * 4;               // bucket totals
    bf16x8* wswz = (bf16x8*)ws; ws += (size_t)2 * L * 2048 * 16;  // swizzled W (256 KB)
    // contiguous zero region: stats | gacc
    float* stats = (float*)ws; ws += (size_t)L * 512 * 4;
    float* gacc  = (float*)ws; ws += (size_t)G * D * 4;

    int zbytes = L * 512 * 4 + G * D * 4;
    int n4 = zbytes / 16;
    k_zero<<<(n4 + 255) / 256, 256, 0, stream>>>((float4*)stats, n4);

    k_prepw<<<2 * L, 256, 0, stream>>>(W1, W2, wswz, L);
    k_hist<<<nbk, 256, 0, stream>>>(edst, cnts, E, nb);
    k_off<<<(nb + 255) / 256, 256, 0, stream>>>(cnts, btot, nbk, nb);
    k_scat<<<nbk, 256, 0, stream>>>(esrc, edst, cnts, pairs, E, nb);
    k_cvt<<<(Mpad * (D / 4) + 255) / 256, 256, 0, stream>>>(x, bufH, M, Mpad);

    int gemm_grid = Mpad / 128;
    int pool_grid = (M + 63) / 64;
    for (int l = 0; l < L; ++l) {
        float* st1 = stats + (size_t)l * 512;
        float* st2 = st1 + 256;
        k_agg<<<nb, 512, 0, stream>>>(bufH, pairs, btot, eps, l, bufP, M, Mpad);
        k_gemm_bf<<<gemm_grid, 256, 0, stream>>>(bufP, bufT, wswz + (size_t)l * 2048,
                                                 b1 + (size_t)l * D, st1, M);
        k_gemm_bn<<<gemm_grid, 256, 0, stream>>>(bufT, wswz + (size_t)(L + l) * 2048,
                                                 b2 + (size_t)l * D, st1,
                                                 g1 + (size_t)l * D, bt1 + (size_t)l * D,
                                                 st2, invM, M);
        k_bn2pool<<<pool_grid, 256, 0, stream>>>(bufT, st2, g2 + (size_t)l * D,
                                                 bt2 + (size_t)l * D, gids, fw, l,
                                                 bufH, gacc, invM, M);
    }
    k_final<<<1, G, 0, stream>>>(gacc, Wp, bp, out);
}

// Round 7
// 808.822 us; speedup vs baseline: 7.8279x; 1.1475x over previous
//
#include <hip/hip_runtime.h>

#define D 128            // hidden dim
#define DOUT 10
#define CT_STRIDE 152    // C-tile LDS row stride in u16 (304 B: 16B-aligned, banks spread)

typedef float f32x4 __attribute__((ext_vector_type(4)));
typedef __bf16 bf16x8 __attribute__((ext_vector_type(8)));
typedef unsigned short u16;

__device__ __forceinline__ float bf2f(u16 u) {
    return __uint_as_float(((unsigned int)u) << 16);
}
__device__ __forceinline__ u16 f2bf(float f) {
    unsigned int u = __float_as_uint(f);
    u += 0x7fffu + ((u >> 16) & 1u);
    return (u16)(u >> 16);
}

// ---------------- zero init (stats | gacc contiguous) ----------------
__global__ void k_zero(float4* __restrict__ p, int n4) {
    int i = blockIdx.x * 256 + threadIdx.x;
    if (i < n4) p[i] = make_float4(0.f, 0.f, 0.f, 0.f);
}

// ---------------- pre-swizzle W1/W2 into MFMA B-fragment order (once per call) -----
// 64 blocks: matrix = blockIdx>>3, quarter = blockIdx&7; one fragment per thread.
__global__ __launch_bounds__(256) void k_prepw(const float* __restrict__ W1,
                                               const float* __restrict__ W2,
                                               bf16x8* __restrict__ wswz, int L) {
    int b = blockIdx.x >> 3;
    const float* W = (b < L) ? (W1 + (size_t)b * D * D)
                             : (W2 + (size_t)(b - L) * D * D);
    bf16x8* o = wswz + (size_t)b * 2048;
    int idx = ((blockIdx.x & 7) << 8) + threadIdx.x;   // 0..2047
    int lane_s = idx & 63;
    int f = idx >> 6;
    int n = ((f >> 2) << 4) | (lane_s & 15);
    int kb = ((f & 3) << 5) | ((lane_s >> 4) << 3);
    bf16x8 fr;
#pragma unroll
    for (int j = 0; j < 8; ++j) fr[j] = (__bf16)W[(kb + j) * D + n];
    o[idx] = fr;
}

// ============ bucketing: deterministic two-level, NO contended global atomics ======
__global__ __launch_bounds__(256) void k_hist(const int* __restrict__ dst,
                                              int* __restrict__ cnts, int E, int nb) {
    __shared__ int hist[1024];
    int tid = threadIdx.x;
    for (int i = tid; i < nb; i += 256) hist[i] = 0;
    __syncthreads();
    int e0 = blockIdx.x << 14;
    int e1 = e0 + 16384; if (e1 > E) e1 = E;
    for (int e = e0 + tid; e < e1; e += 256) atomicAdd(&hist[dst[e] >> 7], 1);
    __syncthreads();
    for (int i = tid; i < nb; i += 256) cnts[(blockIdx.x << 10) + i] = hist[i];
}

__global__ void k_off(int* __restrict__ cnts, int* __restrict__ btot, int nbk, int nb) {
    int b = blockIdx.x * 256 + threadIdx.x;
    if (b >= nb) return;
    int run = 0;
    for (int k = 0; k < nbk; ++k) {
        int idx = (k << 10) + b;
        int c = cnts[idx];
        cnts[idx] = run;
        run += c;
    }
    btot[b] = run;
}

__global__ __launch_bounds__(256) void k_scat(const int* __restrict__ src,
                                              const int* __restrict__ dst,
                                              const int* __restrict__ cnts,
                                              int* __restrict__ pairs, int E, int nb) {
    __shared__ int lbase[1024];
    __shared__ int lcur[1024];
    int tid = threadIdx.x;
    for (int i = tid; i < nb; i += 256) {
        lbase[i] = cnts[(blockIdx.x << 10) + i];
        lcur[i] = 0;
    }
    __syncthreads();
    int e0 = blockIdx.x << 14;
    int e1 = e0 + 16384; if (e1 > E) e1 = E;
    for (int e = e0 + tid; e < e1; e += 256) {
        int d = dst[e];
        int b = d >> 7;
        int pos = lbase[b] + atomicAdd(&lcur[b], 1);
        if (pos < 4096) pairs[(b << 12) + pos] = (src[e] << 7) | (d & 127);
    }
}

// ---------------- x fp32 -> bf16 (padded rows zeroed) ----------------
__global__ void k_cvt(const float* __restrict__ x, u16* __restrict__ o,
                      int M, int Mpad) {
    long e = ((long)blockIdx.x * 256 + threadIdx.x) * 4;
    if (e >= (long)Mpad * D) return;
    ushort4 r;
    if (e < (long)M * D) {
        float4 v = *(const float4*)(x + e);
        r.x = f2bf(v.x); r.y = f2bf(v.y); r.z = f2bf(v.z); r.w = f2bf(v.w);
    } else {
        r = make_ushort4(0, 0, 0, 0);
    }
    *(ushort4*)(o + e) = r;
}

// ---------------- bucket aggregation: local CSR in LDS, register accumulation -----
__global__ __launch_bounds__(512) void k_agg(
        const u16* __restrict__ h, const int* __restrict__ pairs,
        const int* __restrict__ bcnt, const float* __restrict__ eps, int layer,
        u16* __restrict__ out, int M, int Mpad) {
    __shared__ int lcnt[128];
    __shared__ int loff[128];
    __shared__ int lcur[128];
    __shared__ int ledge[4096];
    int tid = threadIdx.x;
    if (tid < 128) lcnt[tid] = 0;
    __syncthreads();

    int b = blockIdx.x;
    int cnt = bcnt[b];
    if (cnt > 4096) cnt = 4096;
    const int* pb = pairs + ((size_t)b << 12);

    for (int e = tid; e < cnt; e += 512)
        atomicAdd(&lcnt[pb[e] & 127], 1);
    __syncthreads();

    if (tid < 128) loff[tid] = lcnt[tid];
    __syncthreads();
    for (int off = 1; off < 128; off <<= 1) {
        int v = 0;
        if (tid < 128 && tid >= off) v = loff[tid - off];
        __syncthreads();
        if (tid < 128) loff[tid] += v;
        __syncthreads();
    }
    if (tid < 128) lcur[tid] = loff[tid] - lcnt[tid];
    __syncthreads();

    for (int e = tid; e < cnt; e += 512) {
        int p = pb[e];
        int pos = atomicAdd(&lcur[p & 127], 1);
        ledge[pos] = p >> 7;
    }
    __syncthreads();

    float e1 = 1.0f + eps[layer];
    int grp = tid >> 5;
    int c = (tid & 31) << 2;
    for (int pass = 0; pass < 8; ++pass) {
        int row = (pass << 4) + grp;
        int node = (b << 7) + row;
        if (node >= Mpad) continue;
        u16* op = out + ((size_t)node << 7) + c;
        if (node >= M) { *(ushort4*)op = make_ushort4(0, 0, 0, 0); continue; }
        ushort4 sv = *(const ushort4*)(h + ((size_t)node << 7) + c);
        float a0 = e1 * bf2f(sv.x), a1 = e1 * bf2f(sv.y);
        float a2 = e1 * bf2f(sv.z), a3 = e1 * bf2f(sv.w);
        int dd = lcnt[row];
        int s = loff[row] - dd;
        int i = 0;
        for (; i + 8 <= dd; i += 8) {
            int n0 = ledge[s + i],     n1 = ledge[s + i + 1];
            int n2 = ledge[s + i + 2], n3 = ledge[s + i + 3];
            int n4 = ledge[s + i + 4], n5 = ledge[s + i + 5];
            int n6 = ledge[s + i + 6], n7 = ledge[s + i + 7];
            ushort4 u0 = *(const ushort4*)(h + ((size_t)n0 << 7) + c);
            ushort4 u1 = *(const ushort4*)(h + ((size_t)n1 << 7) + c);
            ushort4 u2 = *(const ushort4*)(h + ((size_t)n2 << 7) + c);
            ushort4 u3 = *(const ushort4*)(h + ((size_t)n3 << 7) + c);
            ushort4 u4 = *(const ushort4*)(h + ((size_t)n4 << 7) + c);
            ushort4 u5 = *(const ushort4*)(h + ((size_t)n5 << 7) + c);
            ushort4 u6 = *(const ushort4*)(h + ((size_t)n6 << 7) + c);
            ushort4 u7 = *(const ushort4*)(h + ((size_t)n7 << 7) + c);
            a0 += bf2f(u0.x) + bf2f(u1.x) + bf2f(u2.x) + bf2f(u3.x)
                + bf2f(u4.x) + bf2f(u5.x) + bf2f(u6.x) + bf2f(u7.x);
            a1 += bf2f(u0.y) + bf2f(u1.y) + bf2f(u2.y) + bf2f(u3.y)
                + bf2f(u4.y) + bf2f(u5.y) + bf2f(u6.y) + bf2f(u7.y);
            a2 += bf2f(u0.z) + bf2f(u1.z) + bf2f(u2.z) + bf2f(u3.z)
                + bf2f(u4.z) + bf2f(u5.z) + bf2f(u6.z) + bf2f(u7.z);
            a3 += bf2f(u0.w) + bf2f(u1.w) + bf2f(u2.w) + bf2f(u3.w)
                + bf2f(u4.w) + bf2f(u5.w) + bf2f(u6.w) + bf2f(u7.w);
        }
        for (; i + 4 <= dd; i += 4) {
            int n0 = ledge[s + i],     n1 = ledge[s + i + 1];
            int n2 = ledge[s + i + 2], n3 = ledge[s + i + 3];
            ushort4 u0 = *(const ushort4*)(h + ((size_t)n0 << 7) + c);
            ushort4 u1 = *(const ushort4*)(h + ((size_t)n1 << 7) + c);
            ushort4 u2 = *(const ushort4*)(h + ((size_t)n2 << 7) + c);
            ushort4 u3 = *(const ushort4*)(h + ((size_t)n3 << 7) + c);
            a0 += bf2f(u0.x) + bf2f(u1.x) + bf2f(u2.x) + bf2f(u3.x);
            a1 += bf2f(u0.y) + bf2f(u1.y) + bf2f(u2.y) + bf2f(u3.y);
            a2 += bf2f(u0.z) + bf2f(u1.z) + bf2f(u2.z) + bf2f(u3.z);
            a3 += bf2f(u0.w) + bf2f(u1.w) + bf2f(u2.w) + bf2f(u3.w);
        }
        for (; i < dd; ++i) {
            int n0 = ledge[s + i];
            ushort4 u0 = *(const ushort4*)(h + ((size_t)n0 << 7) + c);
            a0 += bf2f(u0.x); a1 += bf2f(u0.y); a2 += bf2f(u0.z); a3 += bf2f(u0.w);
        }
        ushort4 r;
        r.x = f2bf(a0); r.y = f2bf(a1); r.z = f2bf(a2); r.w = f2bf(a3);
        *(ushort4*)op = r;
    }
}

// ---------------- GEMM1: A(bf16) @ W + b -> O(bf16) + BN stats (replicated) --------
// 128-row tile, 4 waves, 2 sub-tiles/wave. Epilogue: C via LDS -> float4 stores;
// stats via shuffle + per-wave LDS slots (no LDS atomics) -> 8-replica global atomics.
__global__ __launch_bounds__(256, 3) void k_gemm_bf(
        const u16* __restrict__ A, u16* __restrict__ O,
        const bf16x8* __restrict__ wz, const float* __restrict__ bias,
        float* __restrict__ stats, int M) {
    __shared__ union { bf16x8 w[2048]; u16 c[128 * CT_STRIDE]; } sh;  // 38.9 KB
    __shared__ float blds[D], psum[4 * D], psq[4 * D];
    int tid = threadIdx.x;
    for (int i = tid; i < 2048; i += 256) sh.w[i] = wz[i];
    if (tid < D) blds[tid] = bias[tid];
    __syncthreads();

    int wave = tid >> 6, lane = tid & 63;
    int m = lane & 15, quad = lane >> 4;
    int row0 = blockIdx.x * 128 + wave * 32;

    f32x4 z = {0.f, 0.f, 0.f, 0.f};
    f32x4 acc0[8], acc1[8];
#pragma unroll
    for (int t = 0; t < 8; ++t) { acc0[t] = z; acc1[t] = z; }

    const u16* ap0 = A + (size_t)(row0 + m) * D + (quad << 3);
    const u16* ap1 = ap0 + (size_t)16 * D;
#pragma unroll
    for (int kc = 0; kc < 4; ++kc) {
        bf16x8 af0 = *(const bf16x8*)(ap0 + (kc << 5));
        bf16x8 af1 = *(const bf16x8*)(ap1 + (kc << 5));
#pragma unroll
        for (int t = 0; t < 8; ++t) {
            bf16x8 bf = sh.w[(((t << 2) | kc) << 6) | lane];
            acc0[t] = __builtin_amdgcn_mfma_f32_16x16x32_bf16(af0, bf, acc0[t], 0, 0, 0);
            acc1[t] = __builtin_amdgcn_mfma_f32_16x16x32_bf16(af1, bf, acc1[t], 0, 0, 0);
        }
    }
    __syncthreads();   // all waves done reading sh.w

    int lr0 = wave * 32 + (quad << 2);
    int gr0 = blockIdx.x * 128 + lr0;
#pragma unroll
    for (int t = 0; t < 8; ++t) {
        int cch = (t << 4) | m;
        float bc = blds[cch];
        float s = 0.f, q = 0.f;
#pragma unroll
        for (int r = 0; r < 4; ++r) {
            float v0 = acc0[t][r] + bc;
            sh.c[(lr0 + r) * CT_STRIDE + cch] = f2bf(v0);
            if (gr0 + r < M) { s += v0; q += v0 * v0; }
            float v1 = acc1[t][r] + bc;
            sh.c[(lr0 + 16 + r) * CT_STRIDE + cch] = f2bf(v1);
            if (gr0 + 16 + r < M) { s += v1; q += v1 * v1; }
        }
        s += __shfl_xor(s, 16); s += __shfl_xor(s, 32);
        q += __shfl_xor(q, 16); q += __shfl_xor(q, 32);
        if (quad == 0) { psum[wave * D + cch] = s; psq[wave * D + cch] = q; }
    }
    __syncthreads();

    int mrow = M - blockIdx.x * 128;   // valid local rows (>=1)
#pragma unroll
    for (int i = 0; i < 8; ++i) {
        int idx = (i << 8) + tid;
        int row = idx >> 4, ch8 = (idx & 15) << 3;
        if (row < mrow) {
            float4 v = *(const float4*)&sh.c[row * CT_STRIDE + ch8];
            *(float4*)(O + ((size_t)(blockIdx.x * 128 + row) << 7) + ch8) = v;
        }
    }
    if (tid < D) {
        float s = psum[tid] + psum[D + tid] + psum[2 * D + tid] + psum[3 * D + tid];
        float q = psq[tid] + psq[D + tid] + psq[2 * D + tid] + psq[3 * D + tid];
        float* st = stats + ((blockIdx.x & 7) << 8);
        atomicAdd(&st[tid], s);
        atomicAdd(&st[D + tid], q);
    }
}

// ---------------- GEMM2: BN1+ReLU on the fly -> @W + b, in-place, + stats2 ---------
__global__ __launch_bounds__(256, 3) void k_gemm_bn(
        u16* __restrict__ A, const bf16x8* __restrict__ wz,
        const float* __restrict__ bias, const float* __restrict__ stats_in,
        const float* __restrict__ gamma, const float* __restrict__ beta,
        float* __restrict__ stats_out, float invM, int M) {
    __shared__ union { bf16x8 w[2048]; u16 c[128 * CT_STRIDE]; } sh;
    __shared__ float blds[D], s_sc[D], s_sh[D], psum[4 * D], psq[4 * D];
    int tid = threadIdx.x;
    for (int i = tid; i < 2048; i += 256) sh.w[i] = wz[i];
    if (tid < D) {
        float s = 0.f, q = 0.f;
#pragma unroll
        for (int r = 0; r < 8; ++r) {
            s += stats_in[(r << 8) + tid];
            q += stats_in[(r << 8) + D + tid];
        }
        float mean = s * invM;
        float var = q * invM - mean * mean;
        float sc = rsqrtf(var + 1e-5f) * gamma[tid];
        s_sc[tid] = sc;
        s_sh[tid] = beta[tid] - mean * sc;
        blds[tid] = bias[tid];
    }
    __syncthreads();

    int wave = tid >> 6, lane = tid & 63;
    int m = lane & 15, quad = lane >> 4;
    int row0 = blockIdx.x * 128 + wave * 32;

    f32x4 z = {0.f, 0.f, 0.f, 0.f};
    f32x4 acc0[8], acc1[8];
#pragma unroll
    for (int t = 0; t < 8; ++t) { acc0[t] = z; acc1[t] = z; }

    const u16* ap0 = A + (size_t)(row0 + m) * D + (quad << 3);
    const u16* ap1 = ap0 + (size_t)16 * D;
#pragma unroll
    for (int kc = 0; kc < 4; ++kc) {
        int kb = (kc << 5) | (quad << 3);
        float4 c0 = *(const float4*)&s_sc[kb];
        float4 c1 = *(const float4*)&s_sc[kb + 4];
        float4 h0 = *(const float4*)&s_sh[kb];
        float4 h1 = *(const float4*)&s_sh[kb + 4];
        ushort4 p0 = *(const ushort4*)(ap0 + (kc << 5));
        ushort4 p1 = *(const ushort4*)(ap0 + (kc << 5) + 4);
        ushort4 q0 = *(const ushort4*)(ap1 + (kc << 5));
        ushort4 q1 = *(const ushort4*)(ap1 + (kc << 5) + 4);
        bf16x8 af0, af1;
        af0[0] = (__bf16)fmaxf(0.f, fmaf(bf2f(p0.x), c0.x, h0.x));
        af0[1] = (__bf16)fmaxf(0.f, fmaf(bf2f(p0.y), c0.y, h0.y));
        af0[2] = (__bf16)fmaxf(0.f, fmaf(bf2f(p0.z), c0.z, h0.z));
        af0[3] = (__bf16)fmaxf(0.f, fmaf(bf2f(p0.w), c0.w, h0.w));
        af0[4] = (__bf16)fmaxf(0.f, fmaf(bf2f(p1.x), c1.x, h1.x));
        af0[5] = (__bf16)fmaxf(0.f, fmaf(bf2f(p1.y), c1.y, h1.y));
        af0[6] = (__bf16)fmaxf(0.f, fmaf(bf2f(p1.z), c1.z, h1.z));
        af0[7] = (__bf16)fmaxf(0.f, fmaf(bf2f(p1.w), c1.w, h1.w));
        af1[0] = (__bf16)fmaxf(0.f, fmaf(bf2f(q0.x), c0.x, h0.x));
        af1[1] = (__bf16)fmaxf(0.f, fmaf(bf2f(q0.y), c0.y, h0.y));
        af1[2] = (__bf16)fmaxf(0.f, fmaf(bf2f(q0.z), c0.z, h0.z));
        af1[3] = (__bf16)fmaxf(0.f, fmaf(bf2f(q0.w), c0.w, h0.w));
        af1[4] = (__bf16)fmaxf(0.f, fmaf(bf2f(q1.x), c1.x, h1.x));
        af1[5] = (__bf16)fmaxf(0.f, fmaf(bf2f(q1.y), c1.y, h1.y));
        af1[6] = (__bf16)fmaxf(0.f, fmaf(bf2f(q1.z), c1.z, h1.z));
        af1[7] = (__bf16)fmaxf(0.f, fmaf(bf2f(q1.w), c1.w, h1.w));
#pragma unroll
        for (int t = 0; t < 8; ++t) {
            bf16x8 bf = sh.w[(((t << 2) | kc) << 6) | lane];
            acc0[t] = __builtin_amdgcn_mfma_f32_16x16x32_bf16(af0, bf, acc0[t], 0, 0, 0);
            acc1[t] = __builtin_amdgcn_mfma_f32_16x16x32_bf16(af1, bf, acc1[t], 0, 0, 0);
        }
    }
    __syncthreads();

    int lr0 = wave * 32 + (quad << 2);
    int gr0 = blockIdx.x * 128 + lr0;
#pragma unroll
    for (int t = 0; t < 8; ++t) {
        int cch = (t << 4) | m;
        float bc = blds[cch];
        float s = 0.f, q = 0.f;
#pragma unroll
        for (int r = 0; r < 4; ++r) {
            float v0 = acc0[t][r] + bc;
            sh.c[(lr0 + r) * CT_STRIDE + cch] = f2bf(v0);
            if (gr0 + r < M) { s += v0; q += v0 * v0; }
            float v1 = acc1[t][r] + bc;
            sh.c[(lr0 + 16 + r) * CT_STRIDE + cch] = f2bf(v1);
            if (gr0 + 16 + r < M) { s += v1; q += v1 * v1; }
        }
        s += __shfl_xor(s, 16); s += __shfl_xor(s, 32);
        q += __shfl_xor(q, 16); q += __shfl_xor(q, 32);
        if (quad == 0) { psum[wave * D + cch] = s; psq[wave * D + cch] = q; }
    }
    __syncthreads();

    int mrow = M - blockIdx.x * 128;
#pragma unroll
    for (int i = 0; i < 8; ++i) {
        int idx = (i << 8) + tid;
        int row = idx >> 4, ch8 = (idx & 15) << 3;
        if (row < mrow) {
            float4 v = *(const float4*)&sh.c[row * CT_STRIDE + ch8];
            *(float4*)(A + ((size_t)(blockIdx.x * 128 + row) << 7) + ch8) = v;
        }
    }
    if (tid < D) {
        float s = psum[tid] + psum[D + tid] + psum[2 * D + tid] + psum[3 * D + tid];
        float q = psq[tid] + psq[D + tid] + psq[2 * D + tid] + psq[3 * D + tid];
        float* st = stats_out + ((blockIdx.x & 7) << 8);
        atomicAdd(&st[tid], s);
        atomicAdd(&st[D + tid], q);
    }
}

// ---------------- BN2 + ReLU -> bf16 h, + fused weighted graph pooling -------------
__global__ __launch_bounds__(256) void k_bn2pool(
        const u16* __restrict__ y, const float* __restrict__ stats,
        const float* __restrict__ gamma, const float* __restrict__ beta,
        const int* __restrict__ gids, const float* __restrict__ fw,
        int layer, u16* __restrict__ hout, float* __restrict__ gacc,
        float invM, int M) {
    int t = threadIdx.x;
    int c = (t & 31) << 2;
    int strip = t >> 5;
    long base = (long)blockIdx.x * 64 + (long)strip * 8;
    if (base >= M) return;
    long nend = base + 8; if (nend > M) nend = M;
    float sc[4], shv[4];
#pragma unroll
    for (int j = 0; j < 4; ++j) {
        float s = 0.f, q = 0.f;
#pragma unroll
        for (int r = 0; r < 8; ++r) {
            s += stats[(r << 8) + c + j];
            q += stats[(r << 8) + D + c + j];
        }
        float mean = s * invM;
        float sv = rsqrtf(q * invM - mean * mean + 1e-5f) * gamma[c + j];
        sc[j] = sv;
        shv[j] = beta[c + j] - mean * sv;
    }
    float wl = fw[layer];
    int cur = -1;
    float a0 = 0.f, a1 = 0.f, a2 = 0.f, a3 = 0.f;
    for (long node = base; node < nend; ++node) {
        ushort4 v = *(const ushort4*)(y + (node << 7) + c);
        float h0 = fmaxf(0.f, fmaf(bf2f(v.x), sc[0], shv[0]));
        float h1 = fmaxf(0.f, fmaf(bf2f(v.y), sc[1], shv[1]));
        float h2 = fmaxf(0.f, fmaf(bf2f(v.z), sc[2], shv[2]));
        float h3 = fmaxf(0.f, fmaf(bf2f(v.w), sc[3], shv[3]));
        ushort4 r;
        r.x = f2bf(h0); r.y = f2bf(h1); r.z = f2bf(h2); r.w = f2bf(h3);
        *(ushort4*)(hout + (node << 7) + c) = r;
        int gid = gids[node];
        if (gid != cur) {
            if (cur >= 0) {
                float* gp = gacc + ((size_t)cur << 7) + c;
                atomicAdd(gp, wl * a0); atomicAdd(gp + 1, wl * a1);
                atomicAdd(gp + 2, wl * a2); atomicAdd(gp + 3, wl * a3);
            }
            cur = gid;
            a0 = a1 = a2 = a3 = 0.f;
        }
        a0 += h0; a1 += h1; a2 += h2; a3 += h3;
    }
    if (cur >= 0) {
        float* gp = gacc + ((size_t)cur << 7) + c;
        atomicAdd(gp, wl * a0); atomicAdd(gp + 1, wl * a1);
        atomicAdd(gp + 2, wl * a2); atomicAdd(gp + 3, wl * a3);
    }
}

// ---------------- final: out = gacc(Gx128) @ Wp(128x10) + bp ----------------
__global__ void k_final(const float* __restrict__ gacc, const float* __restrict__ Wp,
                        const float* __restrict__ bp, float* __restrict__ out) {
    __shared__ float w[D * DOUT];
    __shared__ float bb[DOUT];
    int t = threadIdx.x;
    for (int i = t; i < D * DOUT; i += blockDim.x) w[i] = Wp[i];
    if (t < DOUT) bb[t] = bp[t];
    __syncthreads();
    float acc[DOUT];
#pragma unroll
    for (int o = 0; o < DOUT; ++o) acc[o] = bb[o];
    for (int k = 0; k < D; ++k) {
        float a = gacc[(size_t)t * D + k];
#pragma unroll
        for (int o = 0; o < DOUT; ++o) acc[o] += a * w[k * DOUT + o];
    }
#pragma unroll
    for (int o = 0; o < DOUT; ++o) out[(size_t)t * DOUT + o] = acc[o];
}

extern "C" void kernel_launch(void* const* d_in, const int* in_sizes, int n_in,
                              void* d_out, int out_size, void* d_ws, size_t ws_size,
                              hipStream_t stream) {
    const float* x    = (const float*)d_in[0];
    const int* esrc   = (const int*)d_in[1];
    const int* edst   = (const int*)d_in[2];
    const int* gids   = (const int*)d_in[3];
    const float* eps  = (const float*)d_in[4];
    const float* fw   = (const float*)d_in[5];
    const float* W1   = (const float*)d_in[6];
    const float* b1   = (const float*)d_in[7];
    const float* g1   = (const float*)d_in[8];
    const float* bt1  = (const float*)d_in[9];
    const float* W2   = (const float*)d_in[10];
    const float* b2   = (const float*)d_in[11];
    const float* g2   = (const float*)d_in[12];
    const float* bt2  = (const float*)d_in[13];
    const float* Wp   = (const float*)d_in[14];
    const float* bp   = (const float*)d_in[15];
    float* out        = (float*)d_out;

    const int M = in_sizes[3];     // 100000 nodes
    const int E = in_sizes[1];     // 1600000 edges
    const int L = in_sizes[4];     // 4 layers
    const int G = out_size / DOUT; // 256 graphs
    const int nb  = (M + 127) >> 7;           // buckets of 128 dst nodes (782)
    const int Mpad = nb << 7;
    const int nbk = (E + 16383) >> 14;        // 16K-edge chunks (98)
    const float invM = 1.0f / (float)M;

    char* ws = (char*)d_ws;
    u16* bufP  = (u16*)ws;  ws += (size_t)Mpad * D * 2;   // pooled bf16
    u16* bufT  = (u16*)ws;  ws += (size_t)Mpad * D * 2;   // MLP temp bf16
    u16* bufH  = (u16*)ws;  ws += (size_t)Mpad * D * 2;   // hidden bf16
    int* pairs = (int*)ws;  ws += (size_t)nb * 4096 * 4;  // packed (src<<7)|(dst&127)
    int* cnts  = (int*)ws;  ws += (size_t)nbk * 1024 * 4; // per-(chunk,bucket) bases
    int* btot  = (int*)ws;  ws += 1024 * 4;               // bucket totals
    bf16x8* wswz = (bf16x8*)ws; ws += (size_t)2 * L * 2048 * 16;  // swizzled W
    // contiguous zero region: stats (8 replicas: [rep][{sum,sq}][128]) | gacc
    float* stats = (float*)ws; ws += (size_t)L * 4096 * 4;  // per layer: 2 sets x 2048
    float* gacc  = (float*)ws; ws += (size_t)G * D * 4;

    int zbytes = L * 4096 * 4 + G * D * 4;
    int n4 = zbytes / 16;
    k_zero<<<(n4 + 255) / 256, 256, 0, stream>>>((float4*)stats, n4);

    k_prepw<<<2 * L * 8, 256, 0, stream>>>(W1, W2, wswz, L);
    k_hist<<<nbk, 256, 0, stream>>>(edst, cnts, E, nb);
    k_off<<<(nb + 255) / 256, 256, 0, stream>>>(cnts, btot, nbk, nb);
    k_scat<<<nbk, 256, 0, stream>>>(esrc, edst, cnts, pairs, E, nb);
    k_cvt<<<(Mpad * (D / 4) + 255) / 256, 256, 0, stream>>>(x, bufH, M, Mpad);

    int gemm_grid = Mpad / 128;
    int pool_grid = (M + 63) / 64;
    for (int l = 0; l < L; ++l) {
        float* st1 = stats + (size_t)l * 4096;
        float* st2 = st1 + 2048;
        k_agg<<<nb, 512, 0, stream>>>(bufH, pairs, btot, eps, l, bufP, M, Mpad);
        k_gemm_bf<<<gemm_grid, 256, 0, stream>>>(bufP, bufT, wswz + (size_t)l * 2048,
                                                 b1 + (size_t)l * D, st1, M);
        k_gemm_bn<<<gemm_grid, 256, 0, stream>>>(bufT, wswz + (size_t)(L + l) * 2048,
                                                 b2 + (size_t)l * D, st1,
                                                 g1 + (size_t)l * D, bt1 + (size_t)l * D,
                                                 st2, invM, M);
        k_bn2pool<<<pool_grid, 256, 0, stream>>>(bufT, st2, g2 + (size_t)l * D,
                                                 bt2 + (size_t)l * D, gids, fw, l,
                                                 bufH, gacc, invM, M);
    }
    k_final<<<1, G, 0, stream>>>(gacc, Wp, bp, out);
}